// Round 1
// baseline (516.965 us; speedup 1.0000x reference)
//
#include <hip/hip_runtime.h>

typedef unsigned int u32;
typedef unsigned long long u64;

#define NB 16
#define NA 242991
#define NSEL 4741

__device__ __constant__ int c_LN[5]   = {182400, 45600, 11400, 2850, 741};
__device__ __constant__ int c_LOFF[5] = {0, 182400, 228000, 239400, 242250};
__device__ __constant__ int c_LK[5]   = {1000, 1000, 1000, 1000, 741};
__device__ __constant__ int c_SOFF[5] = {0, 1000, 2000, 3000, 4000};

// ---- XLA-CPU-replicating transcendentals (bitwise-intent, no FMA contraction) ----

__device__ __forceinline__ float xla_tanhf(float x) {
#pragma clang fp contract(off)
  float t = fminf(fmaxf(x, -9.0f), 9.0f);
  float x2 = t * t;
  float p = -2.76076847742355e-16f;
  p = p * x2 + 2.00018790482477e-13f;
  p = p * x2 + -8.60467152213735e-11f;
  p = p * x2 + 5.12229709037114e-08f;
  p = p * x2 + 1.48572235717979e-05f;
  p = p * x2 + 6.37261928875436e-04f;
  p = p * x2 + 4.89352455891786e-03f;
  p = t * p;
  float q = 1.19825839466702e-06f;
  q = q * x2 + 1.18534705686654e-04f;
  q = q * x2 + 2.26843463243900e-03f;
  q = q * x2 + 4.89352518554385e-03f;
  float r = p / q;
  return (fabsf(x) < 0.0004f) ? x : r;
}

__device__ __forceinline__ float ref_sigmoid(float x) {
#pragma clang fp contract(off)
  float t = 0.5f * x;
  float th = xla_tanhf(t);
  return 0.5f + 0.5f * th;
}

__device__ __forceinline__ float xla_expf(float x) {
#pragma clang fp contract(off)
  // Cephes/Eigen-style f32 exp (XLA CPU vectorized expf), plain mul/add.
  float fx = x * 1.44269504088896341f + 0.5f;
  fx = floorf(fx);
  float tmp = fx * 0.693359375f;
  float z = fx * -2.12194440e-4f;
  float r = x - tmp;
  r = r - z;
  float r2 = r * r;
  float y = 1.9875691500e-4f;
  y = y * r + 1.3981999507e-3f;
  y = y * r + 8.3334519073e-3f;
  y = y * r + 4.1665795894e-2f;
  y = y * r + 1.6666665459e-1f;
  y = y * r + 5.0000001201e-1f;
  y = y * r2 + r;
  y = y + 1.0f;
  int k = (int)fx;
  float two_k = __uint_as_float((u32)((k + 127) << 23));
  return y * two_k;
}

// ---- K1: per-(level,batch) exact top-K selection (histogram radix + boundary-bin sort) ----

__global__ void __launch_bounds__(1024) k_select(const float* __restrict__ obj,
                                                 u64* __restrict__ skey) {
  const int l = blockIdx.x, b = blockIdx.y, t = threadIdx.x;
  const int n = c_LN[l], off = c_LOFF[l], K = c_LK[l];
  const float* src = obj + (size_t)b * NA + off;

  __shared__ u32 hist[4096];
  __shared__ u64 cand[2048];
  __shared__ u32 scan[1024];
  __shared__ int sh_bstar;
  __shared__ u32 sh_G, sh_d, sh_c;

  for (int i = t; i < 4096; i += 1024) hist[i] = 0;
  if (t == 0) { sh_d = 0; sh_c = 0; }
  __syncthreads();

  for (int i = t; i < n; i += 1024) {
    float s = ref_sigmoid(src[i]);
    atomicAdd(&hist[__float_as_uint(s) >> 18], 1u);
  }
  __syncthreads();

  // suffix (from-top) scan over 1024 thread-ranges of 4 bins each
  u32 loc = hist[4 * t] + hist[4 * t + 1] + hist[4 * t + 2] + hist[4 * t + 3];
  scan[t] = loc;
  __syncthreads();
  for (int d = 1; d < 1024; d <<= 1) {
    u32 v = (t + d < 1024) ? scan[t + d] : 0u;
    __syncthreads();
    scan[t] += v;
    __syncthreads();
  }
  u32 S = scan[t];
  u32 above = S - loc;  // count in bins strictly above this thread's range
  if (S >= (u32)K && above < (u32)K) {
    u32 c = above;
    for (int bi = 4 * t + 3; bi >= 4 * t; --bi) {
      u32 cn = c + hist[bi];
      if (cn >= (u32)K) { sh_bstar = bi; sh_G = c; break; }
      c = cn;
    }
  }
  __syncthreads();
  const int bstar = sh_bstar;
  const u32 G = sh_G;
  int T = K - (int)G;
  if (T > 2048) T = 2048;  // statistically impossible; bounds safety

  for (int i = t; i < n; i += 1024) {
    float s = ref_sigmoid(src[i]);
    u32 bits = __float_as_uint(s);
    int bin = (int)(bits >> 18);
    if (bin > bstar) {
      u32 p = atomicAdd(&sh_d, 1u);
      skey[(size_t)b * NSEL + c_SOFF[l] + p] =
          ((u64)(bits ^ 0xFFFFFFFFu) << 32) | (u32)(off + i);
    } else if (bin == bstar) {
      u32 p = atomicAdd(&sh_c, 1u);
      if (p < 2048)
        cand[p] = ((u64)(bits ^ 0xFFFFFFFFu) << 32) | (u32)(off + i);
    }
  }
  __syncthreads();
  u32 cc = sh_c; if (cc > 2048) cc = 2048;
  for (int i = t; i < 2048; i += 1024) if (i >= (int)cc) cand[i] = ~0ull;
  __syncthreads();
  // bitonic ascending sort of boundary-bin candidates (key = (~bits)<<32 | idx)
  for (int k = 2; k <= 2048; k <<= 1) {
    for (int j = k >> 1; j > 0; j >>= 1) {
      for (int i = t; i < 2048; i += 1024) {
        int ixj = i ^ j;
        if (ixj > i) {
          u64 a = cand[i], c2 = cand[ixj];
          bool up = ((i & k) == 0);
          if ((a > c2) == up) { cand[i] = c2; cand[ixj] = a; }
        }
      }
      __syncthreads();
    }
  }
  for (int i = t; i < T; i += 1024)
    skey[(size_t)b * NSEL + c_SOFF[l] + G + i] = cand[i];
}

// ---- K2: per-batch global sort of 4741 keys (score desc, idx asc) ----

__global__ void __launch_bounds__(1024) k_sort(u64* __restrict__ skey) {
  const int b = blockIdx.x, t = threadIdx.x;
  extern __shared__ u64 sm[];
  for (int i = t; i < 8192; i += 1024)
    sm[i] = (i < NSEL) ? skey[(size_t)b * NSEL + i] : ~0ull;
  __syncthreads();
  for (int k = 2; k <= 8192; k <<= 1) {
    for (int j = k >> 1; j > 0; j >>= 1) {
      for (int i = t; i < 8192; i += 1024) {
        int ixj = i ^ j;
        if (ixj > i) {
          u64 a = sm[i], c = sm[ixj];
          bool up = ((i & k) == 0);
          if ((a > c) == up) { sm[i] = c; sm[ixj] = a; }
        }
      }
      __syncthreads();
    }
  }
  for (int i = t; i < NSEL; i += 1024) skey[(size_t)b * NSEL + i] = sm[i];
}

// ---- K3: decode boxes, stable per-level ranks, scatter to NMS layout ----

__global__ void __launch_bounds__(1024) k_decode(
    const float* __restrict__ reg, const float* __restrict__ priors,
    const u64* __restrict__ skey, float* __restrict__ boxes,
    float* __restrict__ scoref, u32* __restrict__ levrank,
    float* __restrict__ nmsbox, u64* __restrict__ sow) {
#pragma clang fp contract(off)
  const int b = blockIdx.x, t = threadIdx.x;
  __shared__ u64 csum[1024];
  __shared__ u64 sh_sow[80];
  const int p0 = t * 5;

  u64 key[5];
  int lv[5];
  u64 pack = 0;
  for (int e = 0; e < 5; ++e) {
    int p = p0 + e;
    lv[e] = -1;
    if (p < NSEL) {
      u64 kk = skey[(size_t)b * NSEL + p];
      key[e] = kk;
      u32 idx = (u32)kk;
      int l = (idx < 182400u) ? 0 : (idx < 228000u) ? 1 : (idx < 239400u) ? 2
              : (idx < 242250u) ? 3 : 4;
      lv[e] = l;
      pack += 1ull << (12 * l);
    }
  }
  csum[t] = pack;
  __syncthreads();
  for (int d = 1; d < 1024; d <<= 1) {
    u64 v = (t >= d) ? csum[t - d] : 0ull;
    __syncthreads();
    csum[t] += v;
    __syncthreads();
  }
  u64 base = csum[t] - pack;  // exclusive per-level prefix (5 x 12-bit fields)

  if (t < 80) sh_sow[t] = 0ull;
  __syncthreads();

  for (int e = 0; e < 5; ++e) {
    int p = p0 + e;
    if (p >= NSEL) break;
    int l = lv[e];
    u32 r = (u32)((base >> (12 * l)) & 0xFFFull);
    base += 1ull << (12 * l);
    u64 kk = key[e];
    u32 idx = (u32)kk;
    if (idx >= (u32)NA) idx = NA - 1;  // bounds safety
    u32 bits = (u32)(kk >> 32) ^ 0xFFFFFFFFu;
    float s = __uint_as_float(bits);
    float4 r4 = ((const float4*)reg)[(size_t)b * NA + idx];
    float4 q4 = ((const float4*)priors)[idx];

    float pw = q4.z - q4.x;
    float ph = q4.w - q4.y;
    float pcx = q4.x + 0.5f * pw;
    float pcy = q4.y + 0.5f * ph;
    float dw = fminf(r4.z, 4.135166556742356f);
    float dh = fminf(r4.w, 4.135166556742356f);
    float cx = r4.x * pw + pcx;
    float cy = r4.y * ph + pcy;
    float w = pw * xla_expf(dw);
    float h = ph * xla_expf(dh);
    float x1 = cx - 0.5f * w;
    float y1 = cy - 0.5f * h;
    float x2 = cx + 0.5f * w;
    float y2 = cy + 0.5f * h;
    x1 = fminf(fmaxf(x1, 0.0f), 1216.0f);
    y1 = fminf(fmaxf(y1, 0.0f), 800.0f);
    x2 = fminf(fmaxf(x2, 0.0f), 1216.0f);
    y2 = fminf(fmaxf(y2, 0.0f), 800.0f);
    bool ok = ((x2 - x1) > 0.01f) && ((y2 - y1) > 0.01f);
    float lf = (float)l * 10000.0f;

    float* bo = boxes + ((size_t)b * NSEL + p) * 4;
    bo[0] = x1; bo[1] = y1; bo[2] = x2; bo[3] = y2;
    scoref[(size_t)b * NSEL + p] = s;
    levrank[(size_t)b * NSEL + p] = (u32)l | (r << 4);
    float* nb = nmsbox + (((size_t)(b * 5 + l)) * 1000 + r) * 4;
    nb[0] = x1 + lf; nb[1] = y1 + lf; nb[2] = x2 + lf; nb[3] = y2 + lf;
    if (ok) atomicOr(&sh_sow[l * 16 + (int)(r >> 6)], 1ull << (r & 63));
  }
  __syncthreads();
  if (t < 80) sow[(size_t)b * 80 + t] = sh_sow[t];
}

// ---- K4: per-(level,batch) NMS: parallel suppression mask + single-wave scan ----

__global__ void __launch_bounds__(1024) k_nms(const float* __restrict__ nmsbox,
                                              const u64* __restrict__ sow,
                                              u64* __restrict__ keepw) {
#pragma clang fp contract(off)
  const int l = blockIdx.x, b = blockIdx.y, t = threadIdx.x;
  const int N = c_LK[l], W = (N + 63) >> 6;
  extern __shared__ char smraw[];
  float* bx = (float*)smraw;              // [1000][4]
  float* ar = (float*)(smraw + 16384);    // [1000]
  u64* mk = (u64*)(smraw + 20480);        // [1000][16]

  const float* src = nmsbox + ((size_t)(b * 5 + l)) * 1000 * 4;
  for (int i = t; i < N * 4; i += 1024) bx[i] = src[i];
  __syncthreads();
  for (int i = t; i < N; i += 1024)
    ar[i] = fmaxf(bx[4 * i + 2] - bx[4 * i + 0], 0.0f) *
            fmaxf(bx[4 * i + 3] - bx[4 * i + 1], 0.0f);
  __syncthreads();

  for (int i = t; i < N; i += 1024) {
    float ax1 = bx[4 * i], ay1 = bx[4 * i + 1], ax2 = bx[4 * i + 2],
          ay2 = bx[4 * i + 3], ai = ar[i];
    for (int w = 0; w < W; ++w) {
      u64 m = 0;
      int j0 = w * 64; if (j0 < i + 1) j0 = i + 1;
      int j1 = w * 64 + 64; if (j1 > N) j1 = N;
      for (int j = j0; j < j1; ++j) {
        float xx1 = fmaxf(ax1, bx[4 * j]);
        float yy1 = fmaxf(ay1, bx[4 * j + 1]);
        float xx2 = fminf(ax2, bx[4 * j + 2]);
        float yy2 = fminf(ay2, bx[4 * j + 3]);
        float inter = fmaxf(xx2 - xx1, 0.0f) * fmaxf(yy2 - yy1, 0.0f);
        float den = ((ai + ar[j]) - inter) + 1e-9f;
        float iou = inter / den;
        if (iou > 0.7f) m |= (1ull << (j & 63));
      }
      mk[(size_t)i * 16 + w] = m;
    }
  }
  __syncthreads();

  if (t < 64) {
    u64 rem = 0ull;
    if (t < W) rem = ~sow[(size_t)b * 80 + l * 16 + t];
    for (int i = 0; i < N; ++i) {
      int bit = (int)((rem >> (i & 63)) & 1ull);
      int rbit = __shfl(bit, i >> 6, 64);
      if (!rbit) {
        if (t < W) rem |= mk[(size_t)i * 16 + t];
      }
    }
    if (t < W) keepw[(size_t)b * 80 + l * 16 + t] = ~rem;
  }
}

// ---- K5: keep-compaction and output emit ----

__global__ void __launch_bounds__(1024) k_out(const float* __restrict__ boxes,
                                              const float* __restrict__ scoref,
                                              const u32* __restrict__ levrank,
                                              const u64* __restrict__ keepw,
                                              float* __restrict__ out) {
  const int b = blockIdx.x, t = threadIdx.x;
  __shared__ u32 csum[1024];
  __shared__ u32 sh_tot;
  const int p0 = t * 5;
  int kp[5];
  u32 cnt = 0;
  for (int e = 0; e < 5; ++e) {
    int p = p0 + e;
    kp[e] = 0;
    if (p < NSEL) {
      u32 lr = levrank[(size_t)b * NSEL + p];
      int l = (int)(lr & 15u);
      u32 r = lr >> 4;
      u64 w = keepw[(size_t)b * 80 + l * 16 + (int)(r >> 6)];
      int k = (int)((w >> (r & 63)) & 1ull);
      kp[e] = k;
      cnt += (u32)k;
    }
  }
  csum[t] = cnt;
  __syncthreads();
  for (int d = 1; d < 1024; d <<= 1) {
    u32 v = (t >= d) ? csum[t - d] : 0u;
    __syncthreads();
    csum[t] += v;
    __syncthreads();
  }
  u32 rank = csum[t] - cnt;
  if (t == 1023) sh_tot = csum[1023];
  __syncthreads();
  u32 tot = sh_tot;

  for (int e = 0; e < 5; ++e) {
    int p = p0 + e;
    if (p < NSEL && kp[e]) {
      if (rank < 1000u) {
        const float* bo = boxes + ((size_t)b * NSEL + p) * 4;
        float* o = out + ((size_t)b * 1000 + rank) * 5;
        o[0] = bo[0]; o[1] = bo[1]; o[2] = bo[2]; o[3] = bo[3];
        o[4] = scoref[(size_t)b * NSEL + p];
      }
      rank++;
    }
  }
  for (u32 i = tot + t; i < 1000u; i += 1024u) {
    float* o = out + ((size_t)b * 1000 + i) * 5;
    o[0] = 0.0f; o[1] = 0.0f; o[2] = 0.0f; o[3] = 0.0f; o[4] = 0.0f;
  }
}

// ---- host ----

extern "C" void kernel_launch(void* const* d_in, const int* in_sizes, int n_in,
                              void* d_out, int out_size, void* d_ws, size_t ws_size,
                              hipStream_t stream) {
  const float* reg = (const float*)d_in[0];
  const float* obj = (const float*)d_in[1];
  const float* priors = (const float*)d_in[2];
  float* out = (float*)d_out;

  char* ws = (char*)d_ws;
  size_t off = 0;
  auto alloc = [&](size_t bytes) {
    size_t r = off;
    off += (bytes + 255) & ~(size_t)255;
    return r;
  };
  u64* skey = (u64*)(ws + alloc((size_t)NB * NSEL * 8));
  float* boxes = (float*)(ws + alloc((size_t)NB * NSEL * 16));
  float* scoref = (float*)(ws + alloc((size_t)NB * NSEL * 4));
  u32* levrank = (u32*)(ws + alloc((size_t)NB * NSEL * 4));
  float* nmsbox = (float*)(ws + alloc((size_t)NB * 5 * 1000 * 16));
  u64* sow = (u64*)(ws + alloc((size_t)NB * 80 * 8));
  u64* keepw = (u64*)(ws + alloc((size_t)NB * 80 * 8));

  hipFuncSetAttribute(reinterpret_cast<const void*>(k_sort),
                      hipFuncAttributeMaxDynamicSharedMemorySize, 65536);
  hipFuncSetAttribute(reinterpret_cast<const void*>(k_nms),
                      hipFuncAttributeMaxDynamicSharedMemorySize, 148480);

  k_select<<<dim3(5, NB), 1024, 0, stream>>>(obj, skey);
  k_sort<<<dim3(NB), 1024, 65536, stream>>>(skey);
  k_decode<<<dim3(NB), 1024, 0, stream>>>(reg, priors, skey, boxes, scoref,
                                          levrank, nmsbox, sow);
  k_nms<<<dim3(5, NB), 1024, 148480, stream>>>(nmsbox, sow, keepw);
  k_out<<<dim3(NB), 1024, 0, stream>>>(boxes, scoref, levrank, keepw, out);
}

// Round 2
// 409.680 us; speedup vs baseline: 1.2619x; 1.2619x over previous
//
#include <hip/hip_runtime.h>

typedef unsigned int u32;
typedef unsigned long long u64;

#define NB 16
#define NA 242991
#define NSEL 4741

__device__ __constant__ int c_LN[5]   = {182400, 45600, 11400, 2850, 741};
__device__ __constant__ int c_LOFF[5] = {0, 182400, 228000, 239400, 242250};
__device__ __constant__ int c_LK[5]   = {1000, 1000, 1000, 1000, 741};
__device__ __constant__ int c_SOFF[5] = {0, 1000, 2000, 3000, 4000};

// ---- XLA-CPU-replicating transcendentals (bitwise-intent, no FMA contraction) ----

__device__ __forceinline__ float xla_tanhf(float x) {
#pragma clang fp contract(off)
  float t = fminf(fmaxf(x, -9.0f), 9.0f);
  float x2 = t * t;
  float p = -2.76076847742355e-16f;
  p = p * x2 + 2.00018790482477e-13f;
  p = p * x2 + -8.60467152213735e-11f;
  p = p * x2 + 5.12229709037114e-08f;
  p = p * x2 + 1.48572235717979e-05f;
  p = p * x2 + 6.37261928875436e-04f;
  p = p * x2 + 4.89352455891786e-03f;
  p = t * p;
  float q = 1.19825839466702e-06f;
  q = q * x2 + 1.18534705686654e-04f;
  q = q * x2 + 2.26843463243900e-03f;
  q = q * x2 + 4.89352518554385e-03f;
  float r = p / q;
  return (fabsf(x) < 0.0004f) ? x : r;
}

__device__ __forceinline__ float ref_sigmoid(float x) {
#pragma clang fp contract(off)
  float t = 0.5f * x;
  float th = xla_tanhf(t);
  return 0.5f + 0.5f * th;
}

__device__ __forceinline__ float xla_expf(float x) {
#pragma clang fp contract(off)
  float fx = x * 1.44269504088896341f + 0.5f;
  fx = floorf(fx);
  float tmp = fx * 0.693359375f;
  float z = fx * -2.12194440e-4f;
  float r = x - tmp;
  r = r - z;
  float r2 = r * r;
  float y = 1.9875691500e-4f;
  y = y * r + 1.3981999507e-3f;
  y = y * r + 8.3334519073e-3f;
  y = y * r + 4.1665795894e-2f;
  y = y * r + 1.6666665459e-1f;
  y = y * r + 5.0000001201e-1f;
  y = y * r2 + r;
  y = y + 1.0f;
  int k = (int)fx;
  float two_k = __uint_as_float((u32)((k + 127) << 23));
  return y * two_k;
}

// chunk -> (level, base, n) mapping; 86 chunks of 2850 (level boundaries divide)
__device__ __forceinline__ void chunk_map(int c, int& l, int& base, int& n) {
  if (c < 64)      { l = 0; base = c * 2850;                 n = 2850; }
  else if (c < 80) { l = 1; base = 182400 + (c - 64) * 2850; n = 2850; }
  else if (c < 84) { l = 2; base = 228000 + (c - 80) * 2850; n = 2850; }
  else if (c == 84){ l = 3; base = 239400;                   n = 2850; }
  else             { l = 4; base = 242250;                   n = 741;  }
}

// ---- S1: global per-(b,l) histogram of sigmoid bits (parallel over 86x16 blocks) ----

__global__ void __launch_bounds__(256) k_hist(const float* __restrict__ obj,
                                              u32* __restrict__ ghist) {
  const int c = blockIdx.x, b = blockIdx.y;
  int l, base, n;
  chunk_map(c, l, base, n);
  __shared__ u32 h[4096];
  for (int i = threadIdx.x; i < 4096; i += 256) h[i] = 0;
  __syncthreads();
  const float* src = obj + (size_t)b * NA + base;
  for (int i = threadIdx.x; i < n; i += 256) {
    float s = ref_sigmoid(src[i]);
    atomicAdd(&h[__float_as_uint(s) >> 18], 1u);
  }
  __syncthreads();
  u32* gh = ghist + (size_t)(b * 5 + l) * 4096;
  for (int i = threadIdx.x; i < 4096; i += 256) {
    u32 v = h[i];
    if (v) atomicAdd(&gh[i], v);
  }
}

// ---- S2: per-(b,l) threshold-bin find (suffix scan over 4096 bins) ----

__global__ void __launch_bounds__(1024) k_thresh(const u32* __restrict__ ghist,
                                                 int2* __restrict__ binfo) {
  const int l = blockIdx.x, b = blockIdx.y, t = threadIdx.x;
  const int K = c_LK[l];
  const u32* h = ghist + (size_t)(b * 5 + l) * 4096;
  __shared__ u32 scan[1024];
  __shared__ int sh_b;
  __shared__ u32 sh_G;
  u32 h0 = h[4 * t], h1 = h[4 * t + 1], h2 = h[4 * t + 2], h3 = h[4 * t + 3];
  u32 loc = h0 + h1 + h2 + h3;
  scan[t] = loc;
  __syncthreads();
  for (int d = 1; d < 1024; d <<= 1) {
    u32 v = (t + d < 1024) ? scan[t + d] : 0u;
    __syncthreads();
    scan[t] += v;
    __syncthreads();
  }
  u32 S = scan[t];
  u32 above = S - loc;
  if (S >= (u32)K && above < (u32)K) {
    u32 cacc = above;
    u32 cn = cacc + h3;
    if (cn >= (u32)K) { sh_b = 4 * t + 3; sh_G = cacc; }
    else {
      cacc = cn; cn = cacc + h2;
      if (cn >= (u32)K) { sh_b = 4 * t + 2; sh_G = cacc; }
      else {
        cacc = cn; cn = cacc + h1;
        if (cn >= (u32)K) { sh_b = 4 * t + 1; sh_G = cacc; }
        else { cacc = cn; sh_b = 4 * t; sh_G = cacc; }
      }
    }
  }
  __syncthreads();
  if (t == 0) binfo[b * 5 + l] = make_int2(sh_b, (int)sh_G);
}

// ---- S3: emit selected keys (above-threshold direct, boundary bin to cand buffer) ----

__global__ void __launch_bounds__(256) k_emit(const float* __restrict__ obj,
                                              const int2* __restrict__ binfo,
                                              u64* __restrict__ skey,
                                              u64* __restrict__ candg,
                                              u32* __restrict__ ctrs) {
  const int c = blockIdx.x, b = blockIdx.y;
  int l, base, n;
  chunk_map(c, l, base, n);
  const int bl = b * 5 + l;
  const int bstar = binfo[bl].x;
  const float* src = obj + (size_t)b * NA + base;
  for (int i = threadIdx.x; i < n; i += 256) {
    float s = ref_sigmoid(src[i]);
    u32 bits = __float_as_uint(s);
    int bin = (int)(bits >> 18);
    if (bin >= bstar) {
      u64 key = ((u64)(bits ^ 0xFFFFFFFFu) << 32) | (u32)(base + i);
      if (bin > bstar) {
        u32 p = atomicAdd(&ctrs[bl], 1u);
        skey[(size_t)b * NSEL + c_SOFF[l] + p] = key;
      } else {
        u32 p = atomicAdd(&ctrs[80 + bl], 1u);
        if (p < 2048) candg[(size_t)bl * 2048 + p] = key;
      }
    }
  }
}

// ---- S4: per-(b,l) boundary-bin bitonic sort, write top (K-G) ----

__global__ void __launch_bounds__(1024) k_bsort(const u64* __restrict__ candg,
                                                const int2* __restrict__ binfo,
                                                const u32* __restrict__ ctrs,
                                                u64* __restrict__ skey) {
  const int l = blockIdx.x, b = blockIdx.y, t = threadIdx.x;
  const int bl = b * 5 + l;
  const int K = c_LK[l];
  const u32 G = (u32)binfo[bl].y;
  int T = K - (int)G;
  if (T > 2048) T = 2048;
  u32 cc = ctrs[80 + bl];
  if (cc > 2048) cc = 2048;
  __shared__ u64 cand[2048];
  const u64* src = candg + (size_t)bl * 2048;
  for (int i = t; i < 2048; i += 1024) cand[i] = (i < (int)cc) ? src[i] : ~0ull;
  __syncthreads();
  for (int k = 2; k <= 2048; k <<= 1) {
    for (int j = k >> 1; j > 0; j >>= 1) {
      for (int i = t; i < 2048; i += 1024) {
        int ixj = i ^ j;
        if (ixj > i) {
          u64 a = cand[i], c2 = cand[ixj];
          bool up = ((i & k) == 0);
          if ((a > c2) == up) { cand[i] = c2; cand[ixj] = a; }
        }
      }
      __syncthreads();
    }
  }
  for (int i = t; i < T; i += 1024)
    skey[(size_t)b * NSEL + c_SOFF[l] + G + i] = cand[i];
}

// ---- K2: per-batch global sort of 4741 keys (score desc, idx asc) ----

__global__ void __launch_bounds__(1024) k_sort(u64* __restrict__ skey) {
  const int b = blockIdx.x, t = threadIdx.x;
  extern __shared__ u64 sm[];
  for (int i = t; i < 8192; i += 1024)
    sm[i] = (i < NSEL) ? skey[(size_t)b * NSEL + i] : ~0ull;
  __syncthreads();
  for (int k = 2; k <= 8192; k <<= 1) {
    for (int j = k >> 1; j > 0; j >>= 1) {
      for (int i = t; i < 8192; i += 1024) {
        int ixj = i ^ j;
        if (ixj > i) {
          u64 a = sm[i], c = sm[ixj];
          bool up = ((i & k) == 0);
          if ((a > c) == up) { sm[i] = c; sm[ixj] = a; }
        }
      }
      __syncthreads();
    }
  }
  for (int i = t; i < NSEL; i += 1024) skey[(size_t)b * NSEL + i] = sm[i];
}

// ---- K3: decode boxes, stable per-level ranks, scatter to NMS layout ----

__global__ void __launch_bounds__(1024) k_decode(
    const float* __restrict__ reg, const float* __restrict__ priors,
    const u64* __restrict__ skey, float* __restrict__ boxes,
    float* __restrict__ scoref, u32* __restrict__ levrank,
    float* __restrict__ nmsbox, u64* __restrict__ sow) {
#pragma clang fp contract(off)
  const int b = blockIdx.x, t = threadIdx.x;
  __shared__ u64 csum[1024];
  __shared__ u64 sh_sow[80];
  const int p0 = t * 5;

  u64 key[5];
  int lv[5];
  u64 pack = 0;
  for (int e = 0; e < 5; ++e) {
    int p = p0 + e;
    lv[e] = -1;
    if (p < NSEL) {
      u64 kk = skey[(size_t)b * NSEL + p];
      key[e] = kk;
      u32 idx = (u32)kk;
      int l = (idx < 182400u) ? 0 : (idx < 228000u) ? 1 : (idx < 239400u) ? 2
              : (idx < 242250u) ? 3 : 4;
      lv[e] = l;
      pack += 1ull << (12 * l);
    }
  }
  csum[t] = pack;
  __syncthreads();
  for (int d = 1; d < 1024; d <<= 1) {
    u64 v = (t >= d) ? csum[t - d] : 0ull;
    __syncthreads();
    csum[t] += v;
    __syncthreads();
  }
  u64 base = csum[t] - pack;

  if (t < 80) sh_sow[t] = 0ull;
  __syncthreads();

  for (int e = 0; e < 5; ++e) {
    int p = p0 + e;
    if (p >= NSEL) break;
    int l = lv[e];
    u32 r = (u32)((base >> (12 * l)) & 0xFFFull);
    base += 1ull << (12 * l);
    u64 kk = key[e];
    u32 idx = (u32)kk;
    if (idx >= (u32)NA) idx = NA - 1;
    u32 bits = (u32)(kk >> 32) ^ 0xFFFFFFFFu;
    float s = __uint_as_float(bits);
    float4 r4 = ((const float4*)reg)[(size_t)b * NA + idx];
    float4 q4 = ((const float4*)priors)[idx];

    float pw = q4.z - q4.x;
    float ph = q4.w - q4.y;
    float pcx = q4.x + 0.5f * pw;
    float pcy = q4.y + 0.5f * ph;
    float dw = fminf(r4.z, 4.135166556742356f);
    float dh = fminf(r4.w, 4.135166556742356f);
    float cx = r4.x * pw + pcx;
    float cy = r4.y * ph + pcy;
    float w = pw * xla_expf(dw);
    float h = ph * xla_expf(dh);
    float x1 = cx - 0.5f * w;
    float y1 = cy - 0.5f * h;
    float x2 = cx + 0.5f * w;
    float y2 = cy + 0.5f * h;
    x1 = fminf(fmaxf(x1, 0.0f), 1216.0f);
    y1 = fminf(fmaxf(y1, 0.0f), 800.0f);
    x2 = fminf(fmaxf(x2, 0.0f), 1216.0f);
    y2 = fminf(fmaxf(y2, 0.0f), 800.0f);
    bool ok = ((x2 - x1) > 0.01f) && ((y2 - y1) > 0.01f);
    float lf = (float)l * 10000.0f;

    float* bo = boxes + ((size_t)b * NSEL + p) * 4;
    bo[0] = x1; bo[1] = y1; bo[2] = x2; bo[3] = y2;
    scoref[(size_t)b * NSEL + p] = s;
    levrank[(size_t)b * NSEL + p] = (u32)l | (r << 4);
    float* nb = nmsbox + (((size_t)(b * 5 + l)) * 1000 + r) * 4;
    nb[0] = x1 + lf; nb[1] = y1 + lf; nb[2] = x2 + lf; nb[3] = y2 + lf;
    if (ok) atomicOr(&sh_sow[l * 16 + (int)(r >> 6)], 1ull << (r & 63));
  }
  __syncthreads();
  if (t < 80) sow[(size_t)b * 80 + t] = sh_sow[t];
}

// ---- NMS phase A: parallel suppression-mask build (64 rows/block, 4 rows/thread) ----

__global__ void __launch_bounds__(256) k_nms_build(const float* __restrict__ nmsbox,
                                                   u64* __restrict__ mk) {
#pragma clang fp contract(off)
  const int tile = blockIdx.x, l = blockIdx.y, b = blockIdx.z;
  const int N = c_LK[l];
  const int rbase = tile * 64;
  if (rbase >= N) return;
  __shared__ float sx1[1016], sy1[1016], sx2[1016], sy2[1016];
  const float* src = nmsbox + (size_t)(b * 5 + l) * 1000 * 4;
  for (int j = threadIdx.x; j < N; j += 256) {
    float4 v = ((const float4*)src)[j];
    int p = j + (j >> 6);  // +1 pad per 64: breaks stride-64 bank alias
    sx1[p] = v.x; sy1[p] = v.y; sx2[p] = v.z; sy2[p] = v.w;
  }
  __syncthreads();
  const int r = threadIdx.x >> 4;
  const int w = threadIdx.x & 15;
  u64* dst = mk + (size_t)(b * 5 + l) * 16000;
#pragma unroll
  for (int rr = 0; rr < 4; ++rr) {
    int i = rbase + rr * 16 + r;
    if (i >= N) continue;
    int pi = i + (i >> 6);
    float ax1 = sx1[pi], ay1 = sy1[pi], ax2 = sx2[pi], ay2 = sy2[pi];
    float ai = fmaxf(ax2 - ax1, 0.0f) * fmaxf(ay2 - ay1, 0.0f);
    u64 m = 0;
    int j0 = w * 64; if (j0 < i + 1) j0 = i + 1;
    int j1 = w * 64 + 64; if (j1 > N) j1 = N;
    for (int j = j0; j < j1; ++j) {
      int q = j + w;  // j>>6 == w within this word
      float jx1 = sx1[q], jy1 = sy1[q], jx2 = sx2[q], jy2 = sy2[q];
      float aj = fmaxf(jx2 - jx1, 0.0f) * fmaxf(jy2 - jy1, 0.0f);
      float xx1 = fmaxf(ax1, jx1);
      float yy1 = fmaxf(ay1, jy1);
      float xx2 = fminf(ax2, jx2);
      float yy2 = fminf(ay2, jy2);
      float inter = fmaxf(xx2 - xx1, 0.0f) * fmaxf(yy2 - yy1, 0.0f);
      float den = ((ai + aj) - inter) + 1e-9f;
      float iou = inter / den;
      if (iou > 0.7f) m |= (1ull << (j & 63));
    }
    dst[(size_t)i * 16 + w] = m;
  }
}

// ---- NMS phase B: one wave per (b,l); greedy scan with register-resident rows ----

__global__ void __launch_bounds__(64) k_nms_scan(const u64* __restrict__ mk,
                                                 const u64* __restrict__ sow,
                                                 u64* __restrict__ keepw) {
  const int bl = blockIdx.x;
  const int b = bl / 5, l = bl % 5;
  const int N = c_LK[l];
  const int W = (N + 63) >> 6;
  const int lane = threadIdx.x;
  u64 rem = 0;
  if (lane < W) rem = ~sow[(size_t)b * 80 + l * 16 + lane];
  const u64* base = mk + (size_t)bl * 16000;

#pragma unroll
  for (int g = 0; g < 16; ++g) {
    if (g >= W) break;
    const int gi = g * 64 + lane;
    u64 row[16];
#pragma unroll
    for (int w = g; w < 16; ++w) row[w] = 0;
    if (gi < N) {
      const u64* rp = base + (size_t)gi * 16;
#pragma unroll
      for (int w = g; w < 16; ++w) row[w] = rp[w];
    }
    u64 sup = __shfl(rem, g, 64);  // lane g holds current word-g state
    u64 diag = row[g];
    u64 pend = __ballot(diag != 0) & ~sup;
    while (pend) {
      int i = __builtin_ctzll(pend);
      u64 rr = __shfl(diag, i, 64);
      sup |= rr;
      pend &= ~sup;
      pend &= ~(1ull << i);
    }
    u64 kept = ~sup;
    if (lane == g) rem = sup;
    u64 any = 0;
#pragma unroll
    for (int w = g + 1; w < 16; ++w) any |= row[w];
    if (__ballot(any != 0) & kept) {
#pragma unroll
      for (int w = g + 1; w < 16; ++w) {
        if (__ballot(row[w] != 0) & kept) {
          u64 v = ((kept >> lane) & 1ull) ? row[w] : 0ull;
#pragma unroll
          for (int d = 1; d < 64; d <<= 1) v |= __shfl_xor(v, d, 64);
          if (lane == w) rem |= v;
        }
      }
    }
  }
  if (lane < W) keepw[(size_t)b * 80 + l * 16 + lane] = ~rem;
}

// ---- K5: keep-compaction and output emit ----

__global__ void __launch_bounds__(1024) k_out(const float* __restrict__ boxes,
                                              const float* __restrict__ scoref,
                                              const u32* __restrict__ levrank,
                                              const u64* __restrict__ keepw,
                                              float* __restrict__ out) {
  const int b = blockIdx.x, t = threadIdx.x;
  __shared__ u32 csum[1024];
  __shared__ u32 sh_tot;
  const int p0 = t * 5;
  int kp[5];
  u32 cnt = 0;
  for (int e = 0; e < 5; ++e) {
    int p = p0 + e;
    kp[e] = 0;
    if (p < NSEL) {
      u32 lr = levrank[(size_t)b * NSEL + p];
      int l = (int)(lr & 15u);
      u32 r = lr >> 4;
      u64 w = keepw[(size_t)b * 80 + l * 16 + (int)(r >> 6)];
      int k = (int)((w >> (r & 63)) & 1ull);
      kp[e] = k;
      cnt += (u32)k;
    }
  }
  csum[t] = cnt;
  __syncthreads();
  for (int d = 1; d < 1024; d <<= 1) {
    u32 v = (t >= d) ? csum[t - d] : 0u;
    __syncthreads();
    csum[t] += v;
    __syncthreads();
  }
  u32 rank = csum[t] - cnt;
  if (t == 1023) sh_tot = csum[1023];
  __syncthreads();
  u32 tot = sh_tot;

  for (int e = 0; e < 5; ++e) {
    int p = p0 + e;
    if (p < NSEL && kp[e]) {
      if (rank < 1000u) {
        const float* bo = boxes + ((size_t)b * NSEL + p) * 4;
        float* o = out + ((size_t)b * 1000 + rank) * 5;
        o[0] = bo[0]; o[1] = bo[1]; o[2] = bo[2]; o[3] = bo[3];
        o[4] = scoref[(size_t)b * NSEL + p];
      }
      rank++;
    }
  }
  for (u32 i = tot + t; i < 1000u; i += 1024u) {
    float* o = out + ((size_t)b * 1000 + i) * 5;
    o[0] = 0.0f; o[1] = 0.0f; o[2] = 0.0f; o[3] = 0.0f; o[4] = 0.0f;
  }
}

// ---- host ----

extern "C" void kernel_launch(void* const* d_in, const int* in_sizes, int n_in,
                              void* d_out, int out_size, void* d_ws, size_t ws_size,
                              hipStream_t stream) {
  const float* reg = (const float*)d_in[0];
  const float* obj = (const float*)d_in[1];
  const float* priors = (const float*)d_in[2];
  float* out = (float*)d_out;

  char* ws = (char*)d_ws;
  size_t off = 0;
  auto alloc = [&](size_t bytes) {
    size_t r = off;
    off += (bytes + 255) & ~(size_t)255;
    return r;
  };
  u32* ghist = (u32*)(ws + alloc((size_t)80 * 4096 * 4));
  u32* ctrs = (u32*)(ws + alloc(160 * 4));           // [0..79]=direct, [80..159]=cand
  int2* binfo = (int2*)(ws + alloc(80 * 8));
  u64* candg = (u64*)(ws + alloc((size_t)80 * 2048 * 8));
  u64* skey = (u64*)(ws + alloc((size_t)NB * NSEL * 8));
  float* boxes = (float*)(ws + alloc((size_t)NB * NSEL * 16));
  float* scoref = (float*)(ws + alloc((size_t)NB * NSEL * 4));
  u32* levrank = (u32*)(ws + alloc((size_t)NB * NSEL * 4));
  float* nmsbox = (float*)(ws + alloc((size_t)NB * 5 * 1000 * 16));
  u64* sow = (u64*)(ws + alloc((size_t)NB * 80 * 8));
  u64* keepw = (u64*)(ws + alloc((size_t)NB * 80 * 8));
  u64* mk = (u64*)(ws + alloc((size_t)80 * 1000 * 16 * 8));

  hipFuncSetAttribute(reinterpret_cast<const void*>(k_sort),
                      hipFuncAttributeMaxDynamicSharedMemorySize, 65536);

  hipMemsetAsync(ghist, 0, (size_t)80 * 4096 * 4, stream);
  hipMemsetAsync(ctrs, 0, 160 * 4, stream);

  k_hist<<<dim3(86, NB), 256, 0, stream>>>(obj, ghist);
  k_thresh<<<dim3(5, NB), 1024, 0, stream>>>(ghist, binfo);
  k_emit<<<dim3(86, NB), 256, 0, stream>>>(obj, binfo, skey, candg, ctrs);
  k_bsort<<<dim3(5, NB), 1024, 0, stream>>>(candg, binfo, ctrs, skey);
  k_sort<<<dim3(NB), 1024, 65536, stream>>>(skey);
  k_decode<<<dim3(NB), 1024, 0, stream>>>(reg, priors, skey, boxes, scoref,
                                          levrank, nmsbox, sow);
  k_nms_build<<<dim3(16, 5, NB), 256, 0, stream>>>(nmsbox, mk);
  k_nms_scan<<<dim3(80), 64, 0, stream>>>(mk, sow, keepw);
  k_out<<<dim3(NB), 1024, 0, stream>>>(boxes, scoref, levrank, keepw, out);
}

// Round 3
// 319.478 us; speedup vs baseline: 1.6182x; 1.2823x over previous
//
#include <hip/hip_runtime.h>

typedef unsigned int u32;
typedef unsigned long long u64;

#define NB 16
#define NA 242991
#define NSEL 4741

__device__ __constant__ int c_LN[5]   = {182400, 45600, 11400, 2850, 741};
__device__ __constant__ int c_LOFF[5] = {0, 182400, 228000, 239400, 242250};
__device__ __constant__ int c_LK[5]   = {1000, 1000, 1000, 1000, 741};
__device__ __constant__ int c_SOFF[5] = {0, 1000, 2000, 3000, 4000};

// ---- XLA-CPU-replicating transcendentals (bitwise-intent, no FMA contraction) ----

__device__ __forceinline__ float xla_tanhf(float x) {
#pragma clang fp contract(off)
  float t = fminf(fmaxf(x, -9.0f), 9.0f);
  float x2 = t * t;
  float p = -2.76076847742355e-16f;
  p = p * x2 + 2.00018790482477e-13f;
  p = p * x2 + -8.60467152213735e-11f;
  p = p * x2 + 5.12229709037114e-08f;
  p = p * x2 + 1.48572235717979e-05f;
  p = p * x2 + 6.37261928875436e-04f;
  p = p * x2 + 4.89352455891786e-03f;
  p = t * p;
  float q = 1.19825839466702e-06f;
  q = q * x2 + 1.18534705686654e-04f;
  q = q * x2 + 2.26843463243900e-03f;
  q = q * x2 + 4.89352518554385e-03f;
  float r = p / q;
  return (fabsf(x) < 0.0004f) ? x : r;
}

__device__ __forceinline__ float ref_sigmoid(float x) {
#pragma clang fp contract(off)
  float t = 0.5f * x;
  float th = xla_tanhf(t);
  return 0.5f + 0.5f * th;
}

__device__ __forceinline__ float xla_expf(float x) {
#pragma clang fp contract(off)
  float fx = x * 1.44269504088896341f + 0.5f;
  fx = floorf(fx);
  float tmp = fx * 0.693359375f;
  float z = fx * -2.12194440e-4f;
  float r = x - tmp;
  r = r - z;
  float r2 = r * r;
  float y = 1.9875691500e-4f;
  y = y * r + 1.3981999507e-3f;
  y = y * r + 8.3334519073e-3f;
  y = y * r + 4.1665795894e-2f;
  y = y * r + 1.6666665459e-1f;
  y = y * r + 5.0000001201e-1f;
  y = y * r2 + r;
  y = y + 1.0f;
  int k = (int)fx;
  float two_k = __uint_as_float((u32)((k + 127) << 23));
  return y * two_k;
}

// chunk -> (level, base, n) mapping; 86 chunks of 2850 (level boundaries divide)
__device__ __forceinline__ void chunk_map(int c, int& l, int& base, int& n) {
  if (c < 64)      { l = 0; base = c * 2850;                 n = 2850; }
  else if (c < 80) { l = 1; base = 182400 + (c - 64) * 2850; n = 2850; }
  else if (c < 84) { l = 2; base = 228000 + (c - 80) * 2850; n = 2850; }
  else if (c == 84){ l = 3; base = 239400;                   n = 2850; }
  else             { l = 4; base = 242250;                   n = 741;  }
}

// ---- S1: global per-(b,l) histogram of sigmoid bits ----

__global__ void __launch_bounds__(256) k_hist(const float* __restrict__ obj,
                                              u32* __restrict__ ghist) {
  const int c = blockIdx.x, b = blockIdx.y;
  int l, base, n;
  chunk_map(c, l, base, n);
  __shared__ u32 h[4096];
  for (int i = threadIdx.x; i < 4096; i += 256) h[i] = 0;
  __syncthreads();
  const float* src = obj + (size_t)b * NA + base;
  for (int i = threadIdx.x; i < n; i += 256) {
    float s = ref_sigmoid(src[i]);
    atomicAdd(&h[__float_as_uint(s) >> 18], 1u);
  }
  __syncthreads();
  u32* gh = ghist + (size_t)(b * 5 + l) * 4096;
  for (int i = threadIdx.x; i < 4096; i += 256) {
    u32 v = h[i];
    if (v) atomicAdd(&gh[i], v);
  }
}

// ---- S2: per-(b,l) threshold-bin find ----

__global__ void __launch_bounds__(1024) k_thresh(const u32* __restrict__ ghist,
                                                 int2* __restrict__ binfo) {
  const int l = blockIdx.x, b = blockIdx.y, t = threadIdx.x;
  const int K = c_LK[l];
  const u32* h = ghist + (size_t)(b * 5 + l) * 4096;
  __shared__ u32 scan[1024];
  __shared__ int sh_b;
  __shared__ u32 sh_G;
  u32 h0 = h[4 * t], h1 = h[4 * t + 1], h2 = h[4 * t + 2], h3 = h[4 * t + 3];
  u32 loc = h0 + h1 + h2 + h3;
  scan[t] = loc;
  __syncthreads();
  for (int d = 1; d < 1024; d <<= 1) {
    u32 v = (t + d < 1024) ? scan[t + d] : 0u;
    __syncthreads();
    scan[t] += v;
    __syncthreads();
  }
  u32 S = scan[t];
  u32 above = S - loc;
  if (S >= (u32)K && above < (u32)K) {
    u32 cacc = above;
    u32 cn = cacc + h3;
    if (cn >= (u32)K) { sh_b = 4 * t + 3; sh_G = cacc; }
    else {
      cacc = cn; cn = cacc + h2;
      if (cn >= (u32)K) { sh_b = 4 * t + 2; sh_G = cacc; }
      else {
        cacc = cn; cn = cacc + h1;
        if (cn >= (u32)K) { sh_b = 4 * t + 1; sh_G = cacc; }
        else { cacc = cn; sh_b = 4 * t; sh_G = cacc; }
      }
    }
  }
  __syncthreads();
  if (t == 0) binfo[b * 5 + l] = make_int2(sh_b, (int)sh_G);
}

// ---- S3: emit selected keys ----

__global__ void __launch_bounds__(256) k_emit(const float* __restrict__ obj,
                                              const int2* __restrict__ binfo,
                                              u64* __restrict__ skey,
                                              u64* __restrict__ candg,
                                              u32* __restrict__ ctrs) {
  const int c = blockIdx.x, b = blockIdx.y;
  int l, base, n;
  chunk_map(c, l, base, n);
  const int bl = b * 5 + l;
  const int bstar = binfo[bl].x;
  const float* src = obj + (size_t)b * NA + base;
  for (int i = threadIdx.x; i < n; i += 256) {
    float s = ref_sigmoid(src[i]);
    u32 bits = __float_as_uint(s);
    int bin = (int)(bits >> 18);
    if (bin >= bstar) {
      u64 key = ((u64)(bits ^ 0xFFFFFFFFu) << 32) | (u32)(base + i);
      if (bin > bstar) {
        u32 p = atomicAdd(&ctrs[bl], 1u);
        skey[(size_t)b * NSEL + c_SOFF[l] + p] = key;
      } else {
        u32 p = atomicAdd(&ctrs[80 + bl], 1u);
        if (p < 2048) candg[(size_t)bl * 2048 + p] = key;
      }
    }
  }
}

// ---- S4: per-(b,l) full-segment sort: direct part + boundary candidates -> sorted top-K ----

__global__ void __launch_bounds__(1024) k_selsort(const u64* __restrict__ candg,
                                                  const int2* __restrict__ binfo,
                                                  const u32* __restrict__ ctrs,
                                                  u64* __restrict__ skey) {
  const int l = blockIdx.x, b = blockIdx.y, t = threadIdx.x;
  const int bl = b * 5 + l;
  const int K = c_LK[l];
  const int G = binfo[bl].y;
  u32 cc = ctrs[80 + bl];
  if (cc > 2048) cc = 2048;
  __shared__ u64 sm[4096];
  const u64* seg = skey + (size_t)b * NSEL + c_SOFF[l];
  const u64* cnd = candg + (size_t)bl * 2048;
  for (int i = t; i < 4096; i += 1024) {
    u64 v = ~0ull;
    if (i < G) v = seg[i];
    else if (i - G < (int)cc) v = cnd[i - G];
    sm[i] = v;
  }
  __syncthreads();
  for (int k = 2; k <= 4096; k <<= 1) {
    for (int j = k >> 1; j > 0; j >>= 1) {
      for (int i = t; i < 4096; i += 1024) {
        int ixj = i ^ j;
        if (ixj > i) {
          u64 a = sm[i], c2 = sm[ixj];
          bool up = ((i & k) == 0);
          if ((a > c2) == up) { sm[i] = c2; sm[ixj] = a; }
        }
      }
      __syncthreads();
    }
  }
  for (int i = t; i < K; i += 1024)
    skey[(size_t)b * NSEL + c_SOFF[l] + i] = sm[i];
}

// ---- K3: decode boxes per (level,batch); rank = segment position ----

__global__ void __launch_bounds__(256) k_decode(
    const float* __restrict__ reg, const float* __restrict__ priors,
    const u64* __restrict__ skey, float* __restrict__ boxes,
    float* __restrict__ scoref, float* __restrict__ nmsbox,
    u64* __restrict__ sow) {
#pragma clang fp contract(off)
  const int l = blockIdx.x, b = blockIdx.y, t = threadIdx.x;
  const int K = c_LK[l];
  __shared__ u64 sh_sow[16];
  if (t < 16) sh_sow[t] = 0ull;
  __syncthreads();
  const float lf = (float)l * 10000.0f;
  for (int r = t; r < K; r += 256) {
    u64 kk = skey[(size_t)b * NSEL + c_SOFF[l] + r];
    u32 idx = (u32)kk;
    if (idx >= (u32)NA) idx = NA - 1;
    u32 bits = (u32)(kk >> 32) ^ 0xFFFFFFFFu;
    float s = __uint_as_float(bits);
    float4 r4 = ((const float4*)reg)[(size_t)b * NA + idx];
    float4 q4 = ((const float4*)priors)[idx];

    float pw = q4.z - q4.x;
    float ph = q4.w - q4.y;
    float pcx = q4.x + 0.5f * pw;
    float pcy = q4.y + 0.5f * ph;
    float dw = fminf(r4.z, 4.135166556742356f);
    float dh = fminf(r4.w, 4.135166556742356f);
    float cx = r4.x * pw + pcx;
    float cy = r4.y * ph + pcy;
    float w = pw * xla_expf(dw);
    float h = ph * xla_expf(dh);
    float x1 = cx - 0.5f * w;
    float y1 = cy - 0.5f * h;
    float x2 = cx + 0.5f * w;
    float y2 = cy + 0.5f * h;
    x1 = fminf(fmaxf(x1, 0.0f), 1216.0f);
    y1 = fminf(fmaxf(y1, 0.0f), 800.0f);
    x2 = fminf(fmaxf(x2, 0.0f), 1216.0f);
    y2 = fminf(fmaxf(y2, 0.0f), 800.0f);
    bool ok = ((x2 - x1) > 0.01f) && ((y2 - y1) > 0.01f);

    int sidx = c_SOFF[l] + r;
    ((float4*)boxes)[(size_t)b * NSEL + sidx] = make_float4(x1, y1, x2, y2);
    scoref[(size_t)b * NSEL + sidx] = s;
    ((float4*)nmsbox)[(size_t)(b * 5 + l) * 1000 + r] =
        make_float4(x1 + lf, y1 + lf, x2 + lf, y2 + lf);
    if (ok) atomicOr(&sh_sow[r >> 6], 1ull << (r & 63));
  }
  __syncthreads();
  if (t < 16) sow[(size_t)b * 80 + l * 16 + t] = sh_sow[t];
}

// ---- NMS phase A: parallel suppression-mask build ----

__global__ void __launch_bounds__(256) k_nms_build(const float* __restrict__ nmsbox,
                                                   u64* __restrict__ mk) {
#pragma clang fp contract(off)
  const int tile = blockIdx.x, l = blockIdx.y, b = blockIdx.z;
  const int N = c_LK[l];
  const int rbase = tile * 64;
  if (rbase >= N) return;
  __shared__ float sx1[1016], sy1[1016], sx2[1016], sy2[1016];
  const float* src = nmsbox + (size_t)(b * 5 + l) * 1000 * 4;
  for (int j = threadIdx.x; j < N; j += 256) {
    float4 v = ((const float4*)src)[j];
    int p = j + (j >> 6);
    sx1[p] = v.x; sy1[p] = v.y; sx2[p] = v.z; sy2[p] = v.w;
  }
  __syncthreads();
  const int r = threadIdx.x >> 4;
  const int w = threadIdx.x & 15;
  u64* dst = mk + (size_t)(b * 5 + l) * 16000;
#pragma unroll
  for (int rr = 0; rr < 4; ++rr) {
    int i = rbase + rr * 16 + r;
    if (i >= N) continue;
    int pi = i + (i >> 6);
    float ax1 = sx1[pi], ay1 = sy1[pi], ax2 = sx2[pi], ay2 = sy2[pi];
    float ai = fmaxf(ax2 - ax1, 0.0f) * fmaxf(ay2 - ay1, 0.0f);
    u64 m = 0;
    int j0 = w * 64; if (j0 < i + 1) j0 = i + 1;
    int j1 = w * 64 + 64; if (j1 > N) j1 = N;
    for (int j = j0; j < j1; ++j) {
      int q = j + w;
      float jx1 = sx1[q], jy1 = sy1[q], jx2 = sx2[q], jy2 = sy2[q];
      float aj = fmaxf(jx2 - jx1, 0.0f) * fmaxf(jy2 - jy1, 0.0f);
      float xx1 = fmaxf(ax1, jx1);
      float yy1 = fmaxf(ay1, jy1);
      float xx2 = fminf(ax2, jx2);
      float yy2 = fminf(ay2, jy2);
      float inter = fmaxf(xx2 - xx1, 0.0f) * fmaxf(yy2 - yy1, 0.0f);
      float den = ((ai + aj) - inter) + 1e-9f;
      float iou = inter / den;
      if (iou > 0.7f) m |= (1ull << (j & 63));
    }
    dst[(size_t)i * 16 + w] = m;
  }
}

// ---- NMS phase B: one wave per (b,l); greedy scan, register-resident rows ----

__global__ void __launch_bounds__(64) k_nms_scan(const u64* __restrict__ mk,
                                                 const u64* __restrict__ sow,
                                                 u64* __restrict__ keepw) {
  const int bl = blockIdx.x;
  const int b = bl / 5, l = bl % 5;
  const int N = c_LK[l];
  const int W = (N + 63) >> 6;
  const int lane = threadIdx.x;
  u64 rem = 0;
  if (lane < W) rem = ~sow[(size_t)b * 80 + l * 16 + lane];
  const u64* base = mk + (size_t)bl * 16000;

#pragma unroll
  for (int g = 0; g < 16; ++g) {
    if (g >= W) break;
    const int gi = g * 64 + lane;
    u64 row[16];
#pragma unroll
    for (int w = g; w < 16; ++w) row[w] = 0;
    if (gi < N) {
      const u64* rp = base + (size_t)gi * 16;
#pragma unroll
      for (int w = g; w < 16; ++w) row[w] = rp[w];
    }
    u64 sup = __shfl(rem, g, 64);
    u64 diag = row[g];
    u64 pend = __ballot(diag != 0) & ~sup;
    while (pend) {
      int i = __builtin_ctzll(pend);
      u64 rr = __shfl(diag, i, 64);
      sup |= rr;
      pend &= ~sup;
      pend &= ~(1ull << i);
    }
    u64 kept = ~sup;
    if (lane == g) rem = sup;
    u64 any = 0;
#pragma unroll
    for (int w = g + 1; w < 16; ++w) any |= row[w];
    if (__ballot(any != 0) & kept) {
#pragma unroll
      for (int w = g + 1; w < 16; ++w) {
        if (__ballot(row[w] != 0) & kept) {
          u64 v = ((kept >> lane) & 1ull) ? row[w] : 0ull;
#pragma unroll
          for (int d = 1; d < 64; d <<= 1) v |= __shfl_xor(v, d, 64);
          if (lane == w) rem |= v;
        }
      }
    }
  }
  if (lane < W) keepw[(size_t)b * 80 + l * 16 + lane] = ~rem;
}

// ---- K5: merge 5 sorted kept lists by key; emit top-1000 + zero tail ----

__global__ void __launch_bounds__(1024) k_out(const float* __restrict__ boxes,
                                              const float* __restrict__ scoref,
                                              const u64* __restrict__ skey,
                                              const u64* __restrict__ keepw,
                                              float* __restrict__ out) {
  const int b = blockIdx.x, t = threadIdx.x;
  __shared__ u64 sk[NSEL];
  __shared__ u64 kw[80];
  __shared__ u32 pp[5][17];
  __shared__ u32 sh_T;
  for (int i = t; i < NSEL; i += 1024) sk[i] = skey[(size_t)b * NSEL + i];
  if (t < 80) {
    int l = t >> 4, w = t & 15;
    int W = (c_LK[l] + 63) >> 6;
    kw[t] = (w < W) ? keepw[(size_t)b * 80 + t] : 0ull;
  }
  __syncthreads();
  if (t < 5) {
    u32 acc = 0;
    pp[t][0] = 0;
    for (int w = 0; w < 16; ++w) {
      acc += (u32)__popcll(kw[t * 16 + w]);
      pp[t][w + 1] = acc;
    }
  }
  __syncthreads();
  if (t == 0) sh_T = pp[0][16] + pp[1][16] + pp[2][16] + pp[3][16] + pp[4][16];
  __syncthreads();
  const u32 T = sh_T;

  for (int s = t; s < NSEL; s += 1024) {
    int l = s >> 10;          // s/1024; adjust: levels are 1000-wide
    l = (s >= 4000) ? 4 : (s / 1000);
    int r = s - c_SOFF[l];
    u64 word = kw[l * 16 + (r >> 6)];
    if ((word >> (r & 63)) & 1ull) {
      u32 rank = pp[l][r >> 6] +
                 (u32)__popcll(word & ((r & 63) ? ((1ull << (r & 63)) - 1ull) : 0ull));
      u64 key = sk[s];
#pragma unroll
      for (int l2 = 0; l2 < 5; ++l2) {
        if (l2 == l) continue;
        int lo = 0, hi = c_LK[l2];
        const int base2 = c_SOFF[l2];
        while (lo < hi) {
          int mid = (lo + hi) >> 1;
          if (sk[base2 + mid] < key) lo = mid + 1; else hi = mid;
        }
        u64 w2 = kw[l2 * 16 + (lo >> 6)];
        rank += pp[l2][lo >> 6] +
                (u32)__popcll(w2 & ((lo & 63) ? ((1ull << (lo & 63)) - 1ull) : 0ull));
      }
      if (rank < 1000u) {
        float4 bo = ((const float4*)boxes)[(size_t)b * NSEL + s];
        float* o = out + ((size_t)b * 1000 + rank) * 5;
        o[0] = bo.x; o[1] = bo.y; o[2] = bo.z; o[3] = bo.w;
        o[4] = scoref[(size_t)b * NSEL + s];
      }
    }
  }
  u32 start = (T < 1000u) ? T : 1000u;
  for (u32 i = start + t; i < 1000u; i += 1024u) {
    float* o = out + ((size_t)b * 1000 + i) * 5;
    o[0] = 0.0f; o[1] = 0.0f; o[2] = 0.0f; o[3] = 0.0f; o[4] = 0.0f;
  }
}

// ---- host ----

extern "C" void kernel_launch(void* const* d_in, const int* in_sizes, int n_in,
                              void* d_out, int out_size, void* d_ws, size_t ws_size,
                              hipStream_t stream) {
  const float* reg = (const float*)d_in[0];
  const float* obj = (const float*)d_in[1];
  const float* priors = (const float*)d_in[2];
  float* out = (float*)d_out;

  char* ws = (char*)d_ws;
  size_t off = 0;
  auto alloc = [&](size_t bytes) {
    size_t r = off;
    off += (bytes + 255) & ~(size_t)255;
    return r;
  };
  u32* ghist = (u32*)(ws + alloc((size_t)80 * 4096 * 4));
  u32* ctrs = (u32*)(ws + alloc(160 * 4));
  int2* binfo = (int2*)(ws + alloc(80 * 8));
  u64* candg = (u64*)(ws + alloc((size_t)80 * 2048 * 8));
  u64* skey = (u64*)(ws + alloc((size_t)NB * NSEL * 8));
  float* boxes = (float*)(ws + alloc((size_t)NB * NSEL * 16));
  float* scoref = (float*)(ws + alloc((size_t)NB * NSEL * 4));
  float* nmsbox = (float*)(ws + alloc((size_t)NB * 5 * 1000 * 16));
  u64* sow = (u64*)(ws + alloc((size_t)NB * 80 * 8));
  u64* keepw = (u64*)(ws + alloc((size_t)NB * 80 * 8));
  u64* mk = (u64*)(ws + alloc((size_t)80 * 1000 * 16 * 8));

  hipMemsetAsync(ghist, 0, (size_t)80 * 4096 * 4, stream);
  hipMemsetAsync(ctrs, 0, 160 * 4, stream);

  k_hist<<<dim3(86, NB), 256, 0, stream>>>(obj, ghist);
  k_thresh<<<dim3(5, NB), 1024, 0, stream>>>(ghist, binfo);
  k_emit<<<dim3(86, NB), 256, 0, stream>>>(obj, binfo, skey, candg, ctrs);
  k_selsort<<<dim3(5, NB), 1024, 0, stream>>>(candg, binfo, ctrs, skey);
  k_decode<<<dim3(5, NB), 256, 0, stream>>>(reg, priors, skey, boxes, scoref,
                                            nmsbox, sow);
  k_nms_build<<<dim3(16, 5, NB), 256, 0, stream>>>(nmsbox, mk);
  k_nms_scan<<<dim3(80), 64, 0, stream>>>(mk, sow, keepw);
  k_out<<<dim3(NB), 1024, 0, stream>>>(boxes, scoref, skey, keepw, out);
}

// Round 4
// 287.997 us; speedup vs baseline: 1.7950x; 1.1093x over previous
//
#include <hip/hip_runtime.h>

typedef unsigned int u32;
typedef unsigned long long u64;

#define NB 16
#define NA 242991
#define NSEL 4741

__device__ __constant__ int c_LN[5]   = {182400, 45600, 11400, 2850, 741};
__device__ __constant__ int c_LOFF[5] = {0, 182400, 228000, 239400, 242250};
__device__ __constant__ int c_LK[5]   = {1000, 1000, 1000, 1000, 741};
__device__ __constant__ int c_SOFF[5] = {0, 1000, 2000, 3000, 4000};

// ---- XLA-CPU-replicating transcendentals (bitwise-intent, no FMA contraction) ----

__device__ __forceinline__ float xla_tanhf(float x) {
#pragma clang fp contract(off)
  float t = fminf(fmaxf(x, -9.0f), 9.0f);
  float x2 = t * t;
  float p = -2.76076847742355e-16f;
  p = p * x2 + 2.00018790482477e-13f;
  p = p * x2 + -8.60467152213735e-11f;
  p = p * x2 + 5.12229709037114e-08f;
  p = p * x2 + 1.48572235717979e-05f;
  p = p * x2 + 6.37261928875436e-04f;
  p = p * x2 + 4.89352455891786e-03f;
  p = t * p;
  float q = 1.19825839466702e-06f;
  q = q * x2 + 1.18534705686654e-04f;
  q = q * x2 + 2.26843463243900e-03f;
  q = q * x2 + 4.89352518554385e-03f;
  float r = p / q;
  return (fabsf(x) < 0.0004f) ? x : r;
}

__device__ __forceinline__ float ref_sigmoid(float x) {
#pragma clang fp contract(off)
  float t = 0.5f * x;
  float th = xla_tanhf(t);
  return 0.5f + 0.5f * th;
}

__device__ __forceinline__ float xla_expf(float x) {
#pragma clang fp contract(off)
  float fx = x * 1.44269504088896341f + 0.5f;
  fx = floorf(fx);
  float tmp = fx * 0.693359375f;
  float z = fx * -2.12194440e-4f;
  float r = x - tmp;
  r = r - z;
  float r2 = r * r;
  float y = 1.9875691500e-4f;
  y = y * r + 1.3981999507e-3f;
  y = y * r + 8.3334519073e-3f;
  y = y * r + 4.1665795894e-2f;
  y = y * r + 1.6666665459e-1f;
  y = y * r + 5.0000001201e-1f;
  y = y * r2 + r;
  y = y + 1.0f;
  int k = (int)fx;
  float two_k = __uint_as_float((u32)((k + 127) << 23));
  return y * two_k;
}

// chunk -> (level, base, n) mapping; 86 chunks of 2850 (level boundaries divide)
__device__ __forceinline__ void chunk_map(int c, int& l, int& base, int& n) {
  if (c < 64)      { l = 0; base = c * 2850;                 n = 2850; }
  else if (c < 80) { l = 1; base = 182400 + (c - 64) * 2850; n = 2850; }
  else if (c < 84) { l = 2; base = 228000 + (c - 80) * 2850; n = 2850; }
  else if (c == 84){ l = 3; base = 239400;                   n = 2850; }
  else             { l = 4; base = 242250;                   n = 741;  }
}

// ---- S1: global per-(b,l) histogram of sigmoid bits ----

__global__ void __launch_bounds__(256) k_hist(const float* __restrict__ obj,
                                              u32* __restrict__ ghist) {
  const int c = blockIdx.x, b = blockIdx.y;
  int l, base, n;
  chunk_map(c, l, base, n);
  __shared__ u32 h[4096];
  for (int i = threadIdx.x; i < 4096; i += 256) h[i] = 0;
  __syncthreads();
  const float* src = obj + (size_t)b * NA + base;
  for (int i = threadIdx.x; i < n; i += 256) {
    float s = ref_sigmoid(src[i]);
    atomicAdd(&h[__float_as_uint(s) >> 18], 1u);
  }
  __syncthreads();
  u32* gh = ghist + (size_t)(b * 5 + l) * 4096;
  for (int i = threadIdx.x; i < 4096; i += 256) {
    u32 v = h[i];
    if (v) atomicAdd(&gh[i], v);
  }
}

// ---- S2: per-(b,l) threshold-bin find ----

__global__ void __launch_bounds__(1024) k_thresh(const u32* __restrict__ ghist,
                                                 int2* __restrict__ binfo) {
  const int l = blockIdx.x, b = blockIdx.y, t = threadIdx.x;
  const int K = c_LK[l];
  const u32* h = ghist + (size_t)(b * 5 + l) * 4096;
  __shared__ u32 scan[1024];
  __shared__ int sh_b;
  __shared__ u32 sh_G;
  u32 h0 = h[4 * t], h1 = h[4 * t + 1], h2 = h[4 * t + 2], h3 = h[4 * t + 3];
  u32 loc = h0 + h1 + h2 + h3;
  scan[t] = loc;
  __syncthreads();
  for (int d = 1; d < 1024; d <<= 1) {
    u32 v = (t + d < 1024) ? scan[t + d] : 0u;
    __syncthreads();
    scan[t] += v;
    __syncthreads();
  }
  u32 S = scan[t];
  u32 above = S - loc;
  if (S >= (u32)K && above < (u32)K) {
    u32 cacc = above;
    u32 cn = cacc + h3;
    if (cn >= (u32)K) { sh_b = 4 * t + 3; sh_G = cacc; }
    else {
      cacc = cn; cn = cacc + h2;
      if (cn >= (u32)K) { sh_b = 4 * t + 2; sh_G = cacc; }
      else {
        cacc = cn; cn = cacc + h1;
        if (cn >= (u32)K) { sh_b = 4 * t + 1; sh_G = cacc; }
        else { cacc = cn; sh_b = 4 * t; sh_G = cacc; }
      }
    }
  }
  __syncthreads();
  if (t == 0) binfo[b * 5 + l] = make_int2(sh_b, (int)sh_G);
}

// ---- S3: emit selected keys ----

__global__ void __launch_bounds__(256) k_emit(const float* __restrict__ obj,
                                              const int2* __restrict__ binfo,
                                              u64* __restrict__ skey,
                                              u64* __restrict__ candg,
                                              u32* __restrict__ ctrs) {
  const int c = blockIdx.x, b = blockIdx.y;
  int l, base, n;
  chunk_map(c, l, base, n);
  const int bl = b * 5 + l;
  const int bstar = binfo[bl].x;
  const float* src = obj + (size_t)b * NA + base;
  for (int i = threadIdx.x; i < n; i += 256) {
    float s = ref_sigmoid(src[i]);
    u32 bits = __float_as_uint(s);
    int bin = (int)(bits >> 18);
    if (bin >= bstar) {
      u64 key = ((u64)(bits ^ 0xFFFFFFFFu) << 32) | (u32)(base + i);
      if (bin > bstar) {
        u32 p = atomicAdd(&ctrs[bl], 1u);
        skey[(size_t)b * NSEL + c_SOFF[l] + p] = key;
      } else {
        u32 p = atomicAdd(&ctrs[80 + bl], 1u);
        if (p < 2048) candg[(size_t)bl * 2048 + p] = key;
      }
    }
  }
}

// ---- S4: per-(b,l) full-segment sort -> sorted top-K ----

__global__ void __launch_bounds__(1024) k_selsort(const u64* __restrict__ candg,
                                                  const int2* __restrict__ binfo,
                                                  const u32* __restrict__ ctrs,
                                                  u64* __restrict__ skey) {
  const int l = blockIdx.x, b = blockIdx.y, t = threadIdx.x;
  const int bl = b * 5 + l;
  const int K = c_LK[l];
  const int G = binfo[bl].y;
  u32 cc = ctrs[80 + bl];
  if (cc > 2048) cc = 2048;
  __shared__ u64 sm[4096];
  const u64* seg = skey + (size_t)b * NSEL + c_SOFF[l];
  const u64* cnd = candg + (size_t)bl * 2048;
  for (int i = t; i < 4096; i += 1024) {
    u64 v = ~0ull;
    if (i < G) v = seg[i];
    else if (i - G < (int)cc) v = cnd[i - G];
    sm[i] = v;
  }
  __syncthreads();
  for (int k = 2; k <= 4096; k <<= 1) {
    for (int j = k >> 1; j > 0; j >>= 1) {
      for (int i = t; i < 4096; i += 1024) {
        int ixj = i ^ j;
        if (ixj > i) {
          u64 a = sm[i], c2 = sm[ixj];
          bool up = ((i & k) == 0);
          if ((a > c2) == up) { sm[i] = c2; sm[ixj] = a; }
        }
      }
      __syncthreads();
    }
  }
  for (int i = t; i < K; i += 1024)
    skey[(size_t)b * NSEL + c_SOFF[l] + i] = sm[i];
}

// ---- K3: decode boxes per (level,batch); rank = segment position ----

__global__ void __launch_bounds__(256) k_decode(
    const float* __restrict__ reg, const float* __restrict__ priors,
    const u64* __restrict__ skey, float* __restrict__ boxes,
    float* __restrict__ scoref, float* __restrict__ nmsbox,
    u64* __restrict__ sow) {
#pragma clang fp contract(off)
  const int l = blockIdx.x, b = blockIdx.y, t = threadIdx.x;
  const int K = c_LK[l];
  __shared__ u64 sh_sow[16];
  if (t < 16) sh_sow[t] = 0ull;
  __syncthreads();
  const float lf = (float)l * 10000.0f;
  for (int r = t; r < K; r += 256) {
    u64 kk = skey[(size_t)b * NSEL + c_SOFF[l] + r];
    u32 idx = (u32)kk;
    if (idx >= (u32)NA) idx = NA - 1;
    u32 bits = (u32)(kk >> 32) ^ 0xFFFFFFFFu;
    float s = __uint_as_float(bits);
    float4 r4 = ((const float4*)reg)[(size_t)b * NA + idx];
    float4 q4 = ((const float4*)priors)[idx];

    float pw = q4.z - q4.x;
    float ph = q4.w - q4.y;
    float pcx = q4.x + 0.5f * pw;
    float pcy = q4.y + 0.5f * ph;
    float dw = fminf(r4.z, 4.135166556742356f);
    float dh = fminf(r4.w, 4.135166556742356f);
    float cx = r4.x * pw + pcx;
    float cy = r4.y * ph + pcy;
    float w = pw * xla_expf(dw);
    float h = ph * xla_expf(dh);
    float x1 = cx - 0.5f * w;
    float y1 = cy - 0.5f * h;
    float x2 = cx + 0.5f * w;
    float y2 = cy + 0.5f * h;
    x1 = fminf(fmaxf(x1, 0.0f), 1216.0f);
    y1 = fminf(fmaxf(y1, 0.0f), 800.0f);
    x2 = fminf(fmaxf(x2, 0.0f), 1216.0f);
    y2 = fminf(fmaxf(y2, 0.0f), 800.0f);
    bool ok = ((x2 - x1) > 0.01f) && ((y2 - y1) > 0.01f);

    int sidx = c_SOFF[l] + r;
    ((float4*)boxes)[(size_t)b * NSEL + sidx] = make_float4(x1, y1, x2, y2);
    scoref[(size_t)b * NSEL + sidx] = s;
    ((float4*)nmsbox)[(size_t)(b * 5 + l) * 1000 + r] =
        make_float4(x1 + lf, y1 + lf, x2 + lf, y2 + lf);
    if (ok) atomicOr(&sh_sow[r >> 6], 1ull << (r & 63));
  }
  __syncthreads();
  if (t < 16) sow[(size_t)b * 80 + l * 16 + t] = sh_sow[t];
}

// ---- NMS phase A: upper-triangle 64x64 tiles, one wave per tile ----
// mk layout: per (b,l): [16 words][1000 rows], coalesced in row index.

__device__ __forceinline__ void tile_map(int k, int& l, int& ti, int& tj) {
  int W;
  if (k < 544) { l = k / 136; k -= l * 136; W = 16; }
  else         { l = 4; k -= 544; W = 12; }
  int a = 0;
  while (k >= W - a) { k -= W - a; a++; }
  ti = a; tj = a + k;
}

__device__ __forceinline__ float bcastf(float v, int c) {
  return __uint_as_float((u32)__builtin_amdgcn_readlane((int)__float_as_uint(v), c));
}

__global__ void __launch_bounds__(256) k_nms_build(const float* __restrict__ nmsbox,
                                                   u64* __restrict__ mk) {
#pragma clang fp contract(off)
  const int b = blockIdx.y;
  const int tid = blockIdx.x * 4 + ((int)threadIdx.x >> 6);
  if (tid >= 622) return;
  const int lane = (int)threadIdx.x & 63;
  int l, ti, tj;
  tile_map(tid, l, ti, tj);
  const int N = c_LK[l];
  const int bl = b * 5 + l;
  const float4* src = (const float4*)(nmsbox + (size_t)bl * 4000);
  const int i = ti * 64 + lane;
  const int j = tj * 64 + lane;
  const int il = (i < N) ? i : (N - 1);
  const int jl = (j < N) ? j : (N - 1);
  float4 rb = src[il];
  float4 cb = src[jl];
  float ra = fmaxf(rb.z - rb.x, 0.0f) * fmaxf(rb.w - rb.y, 0.0f);
  float ca = fmaxf(cb.z - cb.x, 0.0f) * fmaxf(cb.w - cb.y, 0.0f);
  u32 mlo = 0u, mhi = 0u;
  // midpoint between 0.7f and nextafter(0.7f): RN32(inter/den) > 0.7f
  // <=> (f64)inter >= M*(f64)den (exact: 25bit x 24bit product fits f64).
  const double M = 0.7000000178813934326171875;
#pragma unroll
  for (int c = 0; c < 64; ++c) {
    float bx1 = bcastf(cb.x, c);
    float by1 = bcastf(cb.y, c);
    float bx2 = bcastf(cb.z, c);
    float by2 = bcastf(cb.w, c);
    float aj = bcastf(ca, c);
    float xx1 = fmaxf(rb.x, bx1);
    float yy1 = fmaxf(rb.y, by1);
    float xx2 = fminf(rb.z, bx2);
    float yy2 = fminf(rb.w, by2);
    float inter = fmaxf(xx2 - xx1, 0.0f) * fmaxf(yy2 - yy1, 0.0f);
    float den = ((ra + aj) - inter) + 1e-9f;
    bool sup = ((double)inter >= M * (double)den);
    if (c < 32) mlo |= sup ? (1u << c) : 0u;
    else        mhi |= sup ? (1u << (c - 32)) : 0u;
  }
  u64 m = ((u64)mhi << 32) | (u64)mlo;
  if (ti == tj) m &= (lane == 63) ? 0ull : (~0ull << (lane + 1));
  int nc = N - tj * 64;
  if (nc < 64) m &= (1ull << nc) - 1ull;
  if (i < N) mk[(size_t)bl * 16000 + (size_t)tj * 1000 + i] = m;
}

// ---- NMS phase B: one wave per (b,l); greedy scan, register-resident rows ----

__global__ void __launch_bounds__(64) k_nms_scan(const u64* __restrict__ mk,
                                                 const u64* __restrict__ sow,
                                                 u64* __restrict__ keepw) {
  const int bl = blockIdx.x;
  const int b = bl / 5, l = bl % 5;
  const int N = c_LK[l];
  const int W = (N + 63) >> 6;
  const int lane = threadIdx.x;
  u64 rem = 0;
  if (lane < W) rem = ~sow[(size_t)b * 80 + l * 16 + lane];
  const u64* base = mk + (size_t)bl * 16000;

#pragma unroll
  for (int g = 0; g < 16; ++g) {
    if (g >= W) break;
    const int gi = g * 64 + lane;
    u64 row[16];
#pragma unroll
    for (int w = g; w < 16; ++w) row[w] = 0;
    if (gi < N) {
#pragma unroll
      for (int w = g; w < 16; ++w)
        if (w < W) row[w] = base[(size_t)w * 1000 + gi];
    }
    u64 sup = __shfl(rem, g, 64);
    u64 diag = row[g];
    u64 pend = __ballot(diag != 0) & ~sup;
    while (pend) {
      int i = __builtin_ctzll(pend);
      u64 rr = __shfl(diag, i, 64);
      sup |= rr;
      pend &= ~sup;
      pend &= ~(1ull << i);
    }
    u64 kept = ~sup;
    if (lane == g) rem = sup;
    u64 any = 0;
#pragma unroll
    for (int w = g + 1; w < 16; ++w) any |= row[w];
    if (__ballot(any != 0) & kept) {
#pragma unroll
      for (int w = g + 1; w < 16; ++w) {
        if (__ballot(row[w] != 0) & kept) {
          u64 v = ((kept >> lane) & 1ull) ? row[w] : 0ull;
#pragma unroll
          for (int d = 1; d < 64; d <<= 1) v |= __shfl_xor(v, d, 64);
          if (lane == w) rem |= v;
        }
      }
    }
  }
  if (lane < W) keepw[(size_t)b * 80 + l * 16 + lane] = ~rem;
}

// ---- K5: merge 5 sorted kept lists by key; emit top-1000 + zero tail ----
// one block per (level, batch): block handles its own segment's kept entries.

__global__ void __launch_bounds__(1024) k_out(const float* __restrict__ boxes,
                                              const float* __restrict__ scoref,
                                              const u64* __restrict__ skey,
                                              const u64* __restrict__ keepw,
                                              float* __restrict__ out) {
  const int l = blockIdx.x, b = blockIdx.y, t = threadIdx.x;
  __shared__ u64 sk[NSEL];
  __shared__ u64 kw[80];
  __shared__ u32 pp[5][17];
  __shared__ u32 sh_T;
  for (int i = t; i < NSEL; i += 1024) sk[i] = skey[(size_t)b * NSEL + i];
  if (t < 80) {
    int l2 = t >> 4, w = t & 15;
    int W = (c_LK[l2] + 63) >> 6;
    kw[t] = (w < W) ? keepw[(size_t)b * 80 + t] : 0ull;
  }
  __syncthreads();
  if (t < 5) {
    u32 acc = 0;
    pp[t][0] = 0;
    for (int w = 0; w < 16; ++w) {
      acc += (u32)__popcll(kw[t * 16 + w]);
      pp[t][w + 1] = acc;
    }
  }
  __syncthreads();
  if (t == 0) sh_T = pp[0][16] + pp[1][16] + pp[2][16] + pp[3][16] + pp[4][16];
  __syncthreads();
  const u32 T = sh_T;
  const int K = c_LK[l];

  for (int r = t; r < K; r += 1024) {
    int s = c_SOFF[l] + r;
    u64 word = kw[l * 16 + (r >> 6)];
    if ((word >> (r & 63)) & 1ull) {
      u32 rank = pp[l][r >> 6] +
                 (u32)__popcll(word & ((r & 63) ? ((1ull << (r & 63)) - 1ull) : 0ull));
      u64 key = sk[s];
#pragma unroll
      for (int l2 = 0; l2 < 5; ++l2) {
        if (l2 == l) continue;
        int lo = 0, hi = c_LK[l2];
        const int base2 = c_SOFF[l2];
        while (lo < hi) {
          int mid = (lo + hi) >> 1;
          if (sk[base2 + mid] < key) lo = mid + 1; else hi = mid;
        }
        u64 w2 = kw[l2 * 16 + (lo >> 6)];
        rank += pp[l2][lo >> 6] +
                (u32)__popcll(w2 & ((lo & 63) ? ((1ull << (lo & 63)) - 1ull) : 0ull));
      }
      if (rank < 1000u) {
        float4 bo = ((const float4*)boxes)[(size_t)b * NSEL + s];
        float* o = out + ((size_t)b * 1000 + rank) * 5;
        o[0] = bo.x; o[1] = bo.y; o[2] = bo.z; o[3] = bo.w;
        o[4] = scoref[(size_t)b * NSEL + s];
      }
    }
  }
  if (l == 0) {
    u32 start = (T < 1000u) ? T : 1000u;
    for (u32 i = start + t; i < 1000u; i += 1024u) {
      float* o = out + ((size_t)b * 1000 + i) * 5;
      o[0] = 0.0f; o[1] = 0.0f; o[2] = 0.0f; o[3] = 0.0f; o[4] = 0.0f;
    }
  }
}

// ---- host ----

extern "C" void kernel_launch(void* const* d_in, const int* in_sizes, int n_in,
                              void* d_out, int out_size, void* d_ws, size_t ws_size,
                              hipStream_t stream) {
  const float* reg = (const float*)d_in[0];
  const float* obj = (const float*)d_in[1];
  const float* priors = (const float*)d_in[2];
  float* out = (float*)d_out;

  char* ws = (char*)d_ws;
  size_t off = 0;
  auto alloc = [&](size_t bytes) {
    size_t r = off;
    off += (bytes + 255) & ~(size_t)255;
    return r;
  };
  u32* ghist = (u32*)(ws + alloc((size_t)80 * 4096 * 4));
  u32* ctrs = (u32*)(ws + alloc(160 * 4));
  int2* binfo = (int2*)(ws + alloc(80 * 8));
  u64* candg = (u64*)(ws + alloc((size_t)80 * 2048 * 8));
  u64* skey = (u64*)(ws + alloc((size_t)NB * NSEL * 8));
  float* boxes = (float*)(ws + alloc((size_t)NB * NSEL * 16));
  float* scoref = (float*)(ws + alloc((size_t)NB * NSEL * 4));
  float* nmsbox = (float*)(ws + alloc((size_t)NB * 5 * 1000 * 16));
  u64* sow = (u64*)(ws + alloc((size_t)NB * 80 * 8));
  u64* keepw = (u64*)(ws + alloc((size_t)NB * 80 * 8));
  u64* mk = (u64*)(ws + alloc((size_t)80 * 1000 * 16 * 8));

  hipMemsetAsync(ghist, 0, (size_t)80 * 4096 * 4, stream);
  hipMemsetAsync(ctrs, 0, 160 * 4, stream);

  k_hist<<<dim3(86, NB), 256, 0, stream>>>(obj, ghist);
  k_thresh<<<dim3(5, NB), 1024, 0, stream>>>(ghist, binfo);
  k_emit<<<dim3(86, NB), 256, 0, stream>>>(obj, binfo, skey, candg, ctrs);
  k_selsort<<<dim3(5, NB), 1024, 0, stream>>>(candg, binfo, ctrs, skey);
  k_decode<<<dim3(5, NB), 256, 0, stream>>>(reg, priors, skey, boxes, scoref,
                                            nmsbox, sow);
  k_nms_build<<<dim3(156, NB), 256, 0, stream>>>(nmsbox, mk);
  k_nms_scan<<<dim3(80), 64, 0, stream>>>(mk, sow, keepw);
  k_out<<<dim3(5, NB), 1024, 0, stream>>>(boxes, scoref, skey, keepw, out);
}

// Round 5
// 222.767 us; speedup vs baseline: 2.3206x; 1.2928x over previous
//
#include <hip/hip_runtime.h>

typedef unsigned int u32;
typedef unsigned long long u64;

#define NB 16
#define NA 242991
#define NSEL 4741

__device__ __constant__ int c_LN[5]   = {182400, 45600, 11400, 2850, 741};
__device__ __constant__ int c_LOFF[5] = {0, 182400, 228000, 239400, 242250};
__device__ __constant__ int c_LK[5]   = {1000, 1000, 1000, 1000, 741};
__device__ __constant__ int c_SOFF[5] = {0, 1000, 2000, 3000, 4000};

// ---- XLA-CPU-replicating transcendentals (bitwise-intent, no FMA contraction) ----

__device__ __forceinline__ float xla_tanhf(float x) {
#pragma clang fp contract(off)
  float t = fminf(fmaxf(x, -9.0f), 9.0f);
  float x2 = t * t;
  float p = -2.76076847742355e-16f;
  p = p * x2 + 2.00018790482477e-13f;
  p = p * x2 + -8.60467152213735e-11f;
  p = p * x2 + 5.12229709037114e-08f;
  p = p * x2 + 1.48572235717979e-05f;
  p = p * x2 + 6.37261928875436e-04f;
  p = p * x2 + 4.89352455891786e-03f;
  p = t * p;
  float q = 1.19825839466702e-06f;
  q = q * x2 + 1.18534705686654e-04f;
  q = q * x2 + 2.26843463243900e-03f;
  q = q * x2 + 4.89352518554385e-03f;
  float r = p / q;
  return (fabsf(x) < 0.0004f) ? x : r;
}

__device__ __forceinline__ float ref_sigmoid(float x) {
#pragma clang fp contract(off)
  float t = 0.5f * x;
  float th = xla_tanhf(t);
  return 0.5f + 0.5f * th;
}

__device__ __forceinline__ float xla_expf(float x) {
#pragma clang fp contract(off)
  float fx = x * 1.44269504088896341f + 0.5f;
  fx = floorf(fx);
  float tmp = fx * 0.693359375f;
  float z = fx * -2.12194440e-4f;
  float r = x - tmp;
  r = r - z;
  float r2 = r * r;
  float y = 1.9875691500e-4f;
  y = y * r + 1.3981999507e-3f;
  y = y * r + 8.3334519073e-3f;
  y = y * r + 4.1665795894e-2f;
  y = y * r + 1.6666665459e-1f;
  y = y * r + 5.0000001201e-1f;
  y = y * r2 + r;
  y = y + 1.0f;
  int k = (int)fx;
  float two_k = __uint_as_float((u32)((k + 127) << 23));
  return y * two_k;
}

// chunk -> (level, base, n) mapping; 86 chunks of 2850 (level boundaries divide)
__device__ __forceinline__ void chunk_map(int c, int& l, int& base, int& n) {
  if (c < 64)      { l = 0; base = c * 2850;                 n = 2850; }
  else if (c < 80) { l = 1; base = 182400 + (c - 64) * 2850; n = 2850; }
  else if (c < 84) { l = 2; base = 228000 + (c - 80) * 2850; n = 2850; }
  else if (c == 84){ l = 3; base = 239400;                   n = 2850; }
  else             { l = 4; base = 242250;                   n = 741;  }
}

// ---- S1: global per-(b,l) histogram of sigmoid bits ----

__global__ void __launch_bounds__(256) k_hist(const float* __restrict__ obj,
                                              u32* __restrict__ ghist) {
  const int c = blockIdx.x, b = blockIdx.y;
  int l, base, n;
  chunk_map(c, l, base, n);
  __shared__ u32 h[4096];
  for (int i = threadIdx.x; i < 4096; i += 256) h[i] = 0;
  __syncthreads();
  const float* src = obj + (size_t)b * NA + base;
  for (int i = threadIdx.x; i < n; i += 256) {
    float s = ref_sigmoid(src[i]);
    atomicAdd(&h[__float_as_uint(s) >> 18], 1u);
  }
  __syncthreads();
  u32* gh = ghist + (size_t)(b * 5 + l) * 4096;
  for (int i = threadIdx.x; i < 4096; i += 256) {
    u32 v = h[i];
    if (v) atomicAdd(&gh[i], v);
  }
}

// ---- S2: per-(b,l) threshold-bin find ----

__global__ void __launch_bounds__(1024) k_thresh(const u32* __restrict__ ghist,
                                                 int2* __restrict__ binfo) {
  const int l = blockIdx.x, b = blockIdx.y, t = threadIdx.x;
  const int K = c_LK[l];
  const u32* h = ghist + (size_t)(b * 5 + l) * 4096;
  __shared__ u32 scan[1024];
  __shared__ int sh_b;
  __shared__ u32 sh_G;
  u32 h0 = h[4 * t], h1 = h[4 * t + 1], h2 = h[4 * t + 2], h3 = h[4 * t + 3];
  u32 loc = h0 + h1 + h2 + h3;
  scan[t] = loc;
  __syncthreads();
  for (int d = 1; d < 1024; d <<= 1) {
    u32 v = (t + d < 1024) ? scan[t + d] : 0u;
    __syncthreads();
    scan[t] += v;
    __syncthreads();
  }
  u32 S = scan[t];
  u32 above = S - loc;
  if (S >= (u32)K && above < (u32)K) {
    u32 cacc = above;
    u32 cn = cacc + h3;
    if (cn >= (u32)K) { sh_b = 4 * t + 3; sh_G = cacc; }
    else {
      cacc = cn; cn = cacc + h2;
      if (cn >= (u32)K) { sh_b = 4 * t + 2; sh_G = cacc; }
      else {
        cacc = cn; cn = cacc + h1;
        if (cn >= (u32)K) { sh_b = 4 * t + 1; sh_G = cacc; }
        else { cacc = cn; sh_b = 4 * t; sh_G = cacc; }
      }
    }
  }
  __syncthreads();
  if (t == 0) binfo[b * 5 + l] = make_int2(sh_b, (int)sh_G);
}

// ---- S3: emit selected keys; ballot-aggregated LDS staging, 2 global atomics/block ----

__global__ void __launch_bounds__(256) k_emit(const float* __restrict__ obj,
                                              const int2* __restrict__ binfo,
                                              u64* __restrict__ skey,
                                              u64* __restrict__ candg,
                                              u32* __restrict__ ctrs) {
  const int c = blockIdx.x, b = blockIdx.y;
  int l, base, n;
  chunk_map(c, l, base, n);
  const int bl = b * 5 + l;
  const int bstar = binfo[bl].x;
  const float* src = obj + (size_t)b * NA + base;

  __shared__ u64 bufD[2880];
  __shared__ u64 bufC[2880];
  __shared__ u32 cntD, cntC, gbD, gbC;
  if (threadIdx.x == 0) { cntD = 0; cntC = 0; }
  __syncthreads();

  const int lane = (int)threadIdx.x & 63;
  const u64 lmask_lt = (lane == 0) ? 0ull : ((~0ull) >> (64 - lane));
  const int iters = (n + 255) >> 8;
  for (int it = 0; it < iters; ++it) {
    int i = it * 256 + (int)threadIdx.x;
    bool valid = i < n;
    float s = ref_sigmoid(valid ? src[i] : 0.0f);
    u32 bits = __float_as_uint(s);
    int bin = (int)(bits >> 18);
    bool isD = valid && (bin > bstar);
    bool isC = valid && (bin == bstar);
    u64 mD = __ballot(isD);
    u64 mC = __ballot(isC);
    u32 bD = 0, bC = 0;
    if (lane == 0) {
      if (mD) bD = atomicAdd(&cntD, (u32)__popcll(mD));
      if (mC) bC = atomicAdd(&cntC, (u32)__popcll(mC));
    }
    bD = (u32)__shfl((int)bD, 0, 64);
    bC = (u32)__shfl((int)bC, 0, 64);
    u64 key = ((u64)(bits ^ 0xFFFFFFFFu) << 32) | (u32)(base + i);
    if (isD) bufD[bD + (u32)__popcll(mD & lmask_lt)] = key;
    if (isC) bufC[bC + (u32)__popcll(mC & lmask_lt)] = key;
  }
  __syncthreads();
  if (threadIdx.x == 0) {
    gbD = atomicAdd(&ctrs[bl], cntD);
    gbC = atomicAdd(&ctrs[80 + bl], cntC);
  }
  __syncthreads();
  const u32 nD = cntD, nC = cntC, gD = gbD, gC = gbC;
  u64* dstD = skey + (size_t)b * NSEL + c_SOFF[l] + gD;
  for (u32 i = threadIdx.x; i < nD; i += 256) dstD[i] = bufD[i];
  u64* dstC = candg + (size_t)bl * 2048;
  for (u32 i = threadIdx.x; i < nC; i += 256) {
    u32 p = gC + i;
    if (p < 2048) dstC[p] = bufC[i];
  }
}

// ---- S4: per-(b,l) full-segment sort -> sorted top-K ----

__global__ void __launch_bounds__(1024) k_selsort(const u64* __restrict__ candg,
                                                  const int2* __restrict__ binfo,
                                                  const u32* __restrict__ ctrs,
                                                  u64* __restrict__ skey) {
  const int l = blockIdx.x, b = blockIdx.y, t = threadIdx.x;
  const int bl = b * 5 + l;
  const int K = c_LK[l];
  const int G = binfo[bl].y;
  u32 cc = ctrs[80 + bl];
  if (cc > 2048) cc = 2048;
  __shared__ u64 sm[4096];
  const u64* seg = skey + (size_t)b * NSEL + c_SOFF[l];
  const u64* cnd = candg + (size_t)bl * 2048;
  for (int i = t; i < 4096; i += 1024) {
    u64 v = ~0ull;
    if (i < G) v = seg[i];
    else if (i - G < (int)cc) v = cnd[i - G];
    sm[i] = v;
  }
  __syncthreads();
  for (int k = 2; k <= 4096; k <<= 1) {
    for (int j = k >> 1; j > 0; j >>= 1) {
      for (int i = t; i < 4096; i += 1024) {
        int ixj = i ^ j;
        if (ixj > i) {
          u64 a = sm[i], c2 = sm[ixj];
          bool up = ((i & k) == 0);
          if ((a > c2) == up) { sm[i] = c2; sm[ixj] = a; }
        }
      }
      __syncthreads();
    }
  }
  for (int i = t; i < K; i += 1024)
    skey[(size_t)b * NSEL + c_SOFF[l] + i] = sm[i];
}

// ---- K3: decode boxes per (level,batch); rank = segment position ----

__global__ void __launch_bounds__(256) k_decode(
    const float* __restrict__ reg, const float* __restrict__ priors,
    const u64* __restrict__ skey, float* __restrict__ boxes,
    float* __restrict__ scoref, float* __restrict__ nmsbox,
    u64* __restrict__ sow) {
#pragma clang fp contract(off)
  const int l = blockIdx.x, b = blockIdx.y, t = threadIdx.x;
  const int K = c_LK[l];
  __shared__ u64 sh_sow[16];
  if (t < 16) sh_sow[t] = 0ull;
  __syncthreads();
  const float lf = (float)l * 10000.0f;
  for (int r = t; r < K; r += 256) {
    u64 kk = skey[(size_t)b * NSEL + c_SOFF[l] + r];
    u32 idx = (u32)kk;
    if (idx >= (u32)NA) idx = NA - 1;
    u32 bits = (u32)(kk >> 32) ^ 0xFFFFFFFFu;
    float s = __uint_as_float(bits);
    float4 r4 = ((const float4*)reg)[(size_t)b * NA + idx];
    float4 q4 = ((const float4*)priors)[idx];

    float pw = q4.z - q4.x;
    float ph = q4.w - q4.y;
    float pcx = q4.x + 0.5f * pw;
    float pcy = q4.y + 0.5f * ph;
    float dw = fminf(r4.z, 4.135166556742356f);
    float dh = fminf(r4.w, 4.135166556742356f);
    float cx = r4.x * pw + pcx;
    float cy = r4.y * ph + pcy;
    float w = pw * xla_expf(dw);
    float h = ph * xla_expf(dh);
    float x1 = cx - 0.5f * w;
    float y1 = cy - 0.5f * h;
    float x2 = cx + 0.5f * w;
    float y2 = cy + 0.5f * h;
    x1 = fminf(fmaxf(x1, 0.0f), 1216.0f);
    y1 = fminf(fmaxf(y1, 0.0f), 800.0f);
    x2 = fminf(fmaxf(x2, 0.0f), 1216.0f);
    y2 = fminf(fmaxf(y2, 0.0f), 800.0f);
    bool ok = ((x2 - x1) > 0.01f) && ((y2 - y1) > 0.01f);

    int sidx = c_SOFF[l] + r;
    ((float4*)boxes)[(size_t)b * NSEL + sidx] = make_float4(x1, y1, x2, y2);
    scoref[(size_t)b * NSEL + sidx] = s;
    ((float4*)nmsbox)[(size_t)(b * 5 + l) * 1000 + r] =
        make_float4(x1 + lf, y1 + lf, x2 + lf, y2 + lf);
    if (ok) atomicOr(&sh_sow[r >> 6], 1ull << (r & 63));
  }
  __syncthreads();
  if (t < 16) sow[(size_t)b * 80 + l * 16 + t] = sh_sow[t];
}

// ---- NMS phase A: upper-triangle 64x64 tiles, one wave per tile ----
// mk layout: per (b,l): [16 words][1000 rows], coalesced in row index.

__device__ __forceinline__ void tile_map(int k, int& l, int& ti, int& tj) {
  int W;
  if (k < 544) { l = k / 136; k -= l * 136; W = 16; }
  else         { l = 4; k -= 544; W = 12; }
  int a = 0;
  while (k >= W - a) { k -= W - a; a++; }
  ti = a; tj = a + k;
}

__device__ __forceinline__ float bcastf(float v, int c) {
  return __uint_as_float((u32)__builtin_amdgcn_readlane((int)__float_as_uint(v), c));
}

__global__ void __launch_bounds__(256) k_nms_build(const float* __restrict__ nmsbox,
                                                   u64* __restrict__ mk) {
#pragma clang fp contract(off)
  const int b = blockIdx.y;
  const int tid = blockIdx.x * 4 + ((int)threadIdx.x >> 6);
  if (tid >= 622) return;
  const int lane = (int)threadIdx.x & 63;
  int l, ti, tj;
  tile_map(tid, l, ti, tj);
  const int N = c_LK[l];
  const int bl = b * 5 + l;
  const float4* src = (const float4*)(nmsbox + (size_t)bl * 4000);
  const int i = ti * 64 + lane;
  const int j = tj * 64 + lane;
  const int il = (i < N) ? i : (N - 1);
  const int jl = (j < N) ? j : (N - 1);
  float4 rb = src[il];
  float4 cb = src[jl];
  float ra = fmaxf(rb.z - rb.x, 0.0f) * fmaxf(rb.w - rb.y, 0.0f);
  float ca = fmaxf(cb.z - cb.x, 0.0f) * fmaxf(cb.w - cb.y, 0.0f);
  u32 mlo = 0u, mhi = 0u;
  // midpoint between 0.7f and nextafter(0.7f): RN32(inter/den) > 0.7f
  // <=> (f64)inter >= M*(f64)den (exact: 25bit x 24bit product fits f64).
  const double M = 0.7000000178813934326171875;
#pragma unroll
  for (int c = 0; c < 64; ++c) {
    float bx1 = bcastf(cb.x, c);
    float by1 = bcastf(cb.y, c);
    float bx2 = bcastf(cb.z, c);
    float by2 = bcastf(cb.w, c);
    float aj = bcastf(ca, c);
    float xx1 = fmaxf(rb.x, bx1);
    float yy1 = fmaxf(rb.y, by1);
    float xx2 = fminf(rb.z, bx2);
    float yy2 = fminf(rb.w, by2);
    float inter = fmaxf(xx2 - xx1, 0.0f) * fmaxf(yy2 - yy1, 0.0f);
    float den = ((ra + aj) - inter) + 1e-9f;
    bool sup = ((double)inter >= M * (double)den);
    if (c < 32) mlo |= sup ? (1u << c) : 0u;
    else        mhi |= sup ? (1u << (c - 32)) : 0u;
  }
  u64 m = ((u64)mhi << 32) | (u64)mlo;
  if (ti == tj) m &= (lane == 63) ? 0ull : (~0ull << (lane + 1));
  int nc = N - tj * 64;
  if (nc < 64) m &= (1ull << nc) - 1ull;
  if (i < N) mk[(size_t)bl * 16000 + (size_t)tj * 1000 + i] = m;
}

// ---- NMS phase B: one wave per (b,l); greedy scan, register-resident rows ----

__global__ void __launch_bounds__(64) k_nms_scan(const u64* __restrict__ mk,
                                                 const u64* __restrict__ sow,
                                                 u64* __restrict__ keepw) {
  const int bl = blockIdx.x;
  const int b = bl / 5, l = bl % 5;
  const int N = c_LK[l];
  const int W = (N + 63) >> 6;
  const int lane = threadIdx.x;
  u64 rem = 0;
  if (lane < W) rem = ~sow[(size_t)b * 80 + l * 16 + lane];
  const u64* base = mk + (size_t)bl * 16000;

#pragma unroll
  for (int g = 0; g < 16; ++g) {
    if (g >= W) break;
    const int gi = g * 64 + lane;
    u64 row[16];
#pragma unroll
    for (int w = g; w < 16; ++w) row[w] = 0;
    if (gi < N) {
#pragma unroll
      for (int w = g; w < 16; ++w)
        if (w < W) row[w] = base[(size_t)w * 1000 + gi];
    }
    u64 sup = __shfl(rem, g, 64);
    u64 diag = row[g];
    u64 pend = __ballot(diag != 0) & ~sup;
    while (pend) {
      int i = __builtin_ctzll(pend);
      u64 rr = __shfl(diag, i, 64);
      sup |= rr;
      pend &= ~sup;
      pend &= ~(1ull << i);
    }
    u64 kept = ~sup;
    if (lane == g) rem = sup;
    u64 any = 0;
#pragma unroll
    for (int w = g + 1; w < 16; ++w) any |= row[w];
    if (__ballot(any != 0) & kept) {
#pragma unroll
      for (int w = g + 1; w < 16; ++w) {
        if (__ballot(row[w] != 0) & kept) {
          u64 v = ((kept >> lane) & 1ull) ? row[w] : 0ull;
#pragma unroll
          for (int d = 1; d < 64; d <<= 1) v |= __shfl_xor(v, d, 64);
          if (lane == w) rem |= v;
        }
      }
    }
  }
  if (lane < W) keepw[(size_t)b * 80 + l * 16 + lane] = ~rem;
}

// ---- K5: merge 5 sorted kept lists by key; emit top-1000 + zero tail ----

__global__ void __launch_bounds__(1024) k_out(const float* __restrict__ boxes,
                                              const float* __restrict__ scoref,
                                              const u64* __restrict__ skey,
                                              const u64* __restrict__ keepw,
                                              float* __restrict__ out) {
  const int l = blockIdx.x, b = blockIdx.y, t = threadIdx.x;
  __shared__ u64 sk[NSEL];
  __shared__ u64 kw[80];
  __shared__ u32 pp[5][17];
  __shared__ u32 sh_T;
  for (int i = t; i < NSEL; i += 1024) sk[i] = skey[(size_t)b * NSEL + i];
  if (t < 80) {
    int l2 = t >> 4, w = t & 15;
    int W = (c_LK[l2] + 63) >> 6;
    kw[t] = (w < W) ? keepw[(size_t)b * 80 + t] : 0ull;
  }
  __syncthreads();
  if (t < 5) {
    u32 acc = 0;
    pp[t][0] = 0;
    for (int w = 0; w < 16; ++w) {
      acc += (u32)__popcll(kw[t * 16 + w]);
      pp[t][w + 1] = acc;
    }
  }
  __syncthreads();
  if (t == 0) sh_T = pp[0][16] + pp[1][16] + pp[2][16] + pp[3][16] + pp[4][16];
  __syncthreads();
  const u32 T = sh_T;
  const int K = c_LK[l];

  for (int r = t; r < K; r += 1024) {
    int s = c_SOFF[l] + r;
    u64 word = kw[l * 16 + (r >> 6)];
    if ((word >> (r & 63)) & 1ull) {
      u32 rank = pp[l][r >> 6] +
                 (u32)__popcll(word & ((r & 63) ? ((1ull << (r & 63)) - 1ull) : 0ull));
      u64 key = sk[s];
#pragma unroll
      for (int l2 = 0; l2 < 5; ++l2) {
        if (l2 == l) continue;
        int lo = 0, hi = c_LK[l2];
        const int base2 = c_SOFF[l2];
        while (lo < hi) {
          int mid = (lo + hi) >> 1;
          if (sk[base2 + mid] < key) lo = mid + 1; else hi = mid;
        }
        u64 w2 = kw[l2 * 16 + (lo >> 6)];
        rank += pp[l2][lo >> 6] +
                (u32)__popcll(w2 & ((lo & 63) ? ((1ull << (lo & 63)) - 1ull) : 0ull));
      }
      if (rank < 1000u) {
        float4 bo = ((const float4*)boxes)[(size_t)b * NSEL + s];
        float* o = out + ((size_t)b * 1000 + rank) * 5;
        o[0] = bo.x; o[1] = bo.y; o[2] = bo.z; o[3] = bo.w;
        o[4] = scoref[(size_t)b * NSEL + s];
      }
    }
  }
  if (l == 0) {
    u32 start = (T < 1000u) ? T : 1000u;
    for (u32 i = start + t; i < 1000u; i += 1024u) {
      float* o = out + ((size_t)b * 1000 + i) * 5;
      o[0] = 0.0f; o[1] = 0.0f; o[2] = 0.0f; o[3] = 0.0f; o[4] = 0.0f;
    }
  }
}

// ---- host ----

extern "C" void kernel_launch(void* const* d_in, const int* in_sizes, int n_in,
                              void* d_out, int out_size, void* d_ws, size_t ws_size,
                              hipStream_t stream) {
  const float* reg = (const float*)d_in[0];
  const float* obj = (const float*)d_in[1];
  const float* priors = (const float*)d_in[2];
  float* out = (float*)d_out;

  char* ws = (char*)d_ws;
  size_t off = 0;
  auto alloc = [&](size_t bytes) {
    size_t r = off;
    off += (bytes + 255) & ~(size_t)255;
    return r;
  };
  u32* ghist = (u32*)(ws + alloc((size_t)80 * 4096 * 4));
  u32* ctrs = (u32*)(ws + alloc(160 * 4));
  int2* binfo = (int2*)(ws + alloc(80 * 8));
  u64* candg = (u64*)(ws + alloc((size_t)80 * 2048 * 8));
  u64* skey = (u64*)(ws + alloc((size_t)NB * NSEL * 8));
  float* boxes = (float*)(ws + alloc((size_t)NB * NSEL * 16));
  float* scoref = (float*)(ws + alloc((size_t)NB * NSEL * 4));
  float* nmsbox = (float*)(ws + alloc((size_t)NB * 5 * 1000 * 16));
  u64* sow = (u64*)(ws + alloc((size_t)NB * 80 * 8));
  u64* keepw = (u64*)(ws + alloc((size_t)NB * 80 * 8));
  u64* mk = (u64*)(ws + alloc((size_t)80 * 1000 * 16 * 8));

  hipMemsetAsync(ghist, 0, (size_t)80 * 4096 * 4, stream);
  hipMemsetAsync(ctrs, 0, 160 * 4, stream);

  k_hist<<<dim3(86, NB), 256, 0, stream>>>(obj, ghist);
  k_thresh<<<dim3(5, NB), 1024, 0, stream>>>(ghist, binfo);
  k_emit<<<dim3(86, NB), 256, 0, stream>>>(obj, binfo, skey, candg, ctrs);
  k_selsort<<<dim3(5, NB), 1024, 0, stream>>>(candg, binfo, ctrs, skey);
  k_decode<<<dim3(5, NB), 256, 0, stream>>>(reg, priors, skey, boxes, scoref,
                                            nmsbox, sow);
  k_nms_build<<<dim3(156, NB), 256, 0, stream>>>(nmsbox, mk);
  k_nms_scan<<<dim3(80), 64, 0, stream>>>(mk, sow, keepw);
  k_out<<<dim3(5, NB), 1024, 0, stream>>>(boxes, scoref, skey, keepw, out);
}